// Round 1
// 533.797 us; speedup vs baseline: 1.0566x; 1.0566x over previous
//
#include <hip/hip_runtime.h>
#include <hip/hip_bf16.h>

// RGCN 2-layer encoder. N=50000, R=16, B=8, Dim=128, E=625000.
// fp32 in/out (runtime-detected), bf16 MFMA internals.
//
// R17 (aggregate-first restructure): mean-aggregation commutes with the
// per-relation linear map, so aggregate x per (node,rel) FIRST (gather from
// the 12.8MB L2/L3-resident x table instead of the 204.8MB ygrp table),
// write Hall[N][2048] bf16, then ONE fused GEMM per layer with K=2176
// (16 relations + self) and bias+LN+ReLU in the epilogue. Deletes selfgemm,
// the fp32 acc round-trip, and the agg-finalize pass. 15 dispatches.
//
// Pipeline per layer: wallT[r][o][k]=W[r]^T (slot16=selfw^T);
// agg2: wave-per-node CSR scan -> Hall[n][r*128+o] = mean_r(x[col]);
// fusegemm: out[n][o] = [Hall[n] | x[n]] @ wallT (K=2176), epilogue LN+ReLU.

static constexpr int kDim = 128;
static constexpr int kRel = 16;

typedef __attribute__((ext_vector_type(8))) short bf16x8;
typedef __attribute__((ext_vector_type(4))) float f32x4;

static __device__ __forceinline__ float bf2f_rg(unsigned short h) {
    return __uint_as_float(((unsigned)h) << 16);
}
static __device__ __forceinline__ unsigned short f2bf_rg(float f) {
    unsigned u = __float_as_uint(f);
    u = u + 0x7fffu + ((u >> 16) & 1u);   // round-to-nearest-even
    return (unsigned short)(u >> 16);
}

// template-named kernel: sentinel fill (fully overwritten by pipeline)
__global__ void RGCNEncoder_89962384982025_kernel(unsigned* p, int n) {
    int i = blockIdx.x * 256 + threadIdx.x;
    if (i < n) p[i] = 0x3F803F80u;
}

// dtype detection: any bf16-decoded |v|>=128/inf/nan in first 128 halves => fp32
__global__ void detect_rg(const unsigned short* x, int* dflag) {
    if (blockIdx.x == 0 && threadIdx.x == 0) {
        int insane = 0;
        for (int i = 0; i < 128; ++i) {
            unsigned e = ((unsigned)x[i] >> 7) & 0xFFu;
            if (e >= 0x86u) insane = 1;
        }
        *dflag = insane;
    }
}

// convert emb (fp32 or bf16 per flag) -> bf16 xin
__global__ void cvt_rg(const void* xraw, const int* dflag, unsigned short* xout, int n) {
    int i = blockIdx.x * 256 + threadIdx.x;
    if (i >= n) return;
    if (*dflag)
        xout[i] = f2bf_rg(((const float*)xraw)[i]);
    else
        xout[i] = ((const unsigned short*)xraw)[i];
}

__global__ void zero_rg(int* p, int n) {
    int i = blockIdx.x * 256 + threadIdx.x;
    if (i < n) p[i] = 0;
}

__global__ void count_rg(const int* ei, const int* et, int* cnt, int E) {
    int e = blockIdx.x * 256 + threadIdx.x;
    if (e < E) atomicAdd(&cnt[ei[e] * kRel + et[e]], 1);
}

// hierarchical scan, in place on rowptr (saves the incl buffer)
__global__ void scanA_rg(const int* cnt, int* rowptr, int* bsum, int n) {
    __shared__ int sh[256];
    int tid = threadIdx.x;
    int i = blockIdx.x * 256 + tid;
    int v = (i < n) ? cnt[i] : 0;
    sh[tid] = v;
    __syncthreads();
    for (int off = 1; off < 256; off <<= 1) {
        int t = (tid >= off) ? sh[tid - off] : 0;
        __syncthreads();
        sh[tid] += t;
        __syncthreads();
    }
    if (i < n) rowptr[i + 1] = sh[tid];
    if (tid == 255) bsum[blockIdx.x] = sh[255];
}
__global__ void scanB_rg(int* bsum, int nb) {
    __shared__ int partial[256];
    int tid = threadIdx.x;
    int chunk = (nb + 255) / 256;
    int s0 = tid * chunk;
    int s1 = min(s0 + chunk, nb);
    int sum = 0;
    for (int i = s0; i < s1; ++i) sum += bsum[i];
    partial[tid] = sum;
    __syncthreads();
    for (int off = 1; off < 256; off <<= 1) {
        int t = (tid >= off) ? partial[tid - off] : 0;
        __syncthreads();
        partial[tid] += t;
        __syncthreads();
    }
    int run = (tid == 0) ? 0 : partial[tid - 1];
    for (int i = s0; i < s1; ++i) { int v = bsum[i]; bsum[i] = run; run += v; }
}
__global__ void scanC_rg(int* rowptr, const int* bsum, int n) {
    int i = blockIdx.x * 256 + threadIdx.x;
    if (i < n) rowptr[i + 1] += bsum[blockIdx.x];
    if (i == 0) rowptr[0] = 0;
}

// fill: pcols entry packs col | rel<<26 (col < 2^26)
__global__ void fill_rg(const int* ei, const int* et, const int* rowptr,
                        int* cnt, int* pcols, int E) {
    int e = blockIdx.x * 256 + threadIdx.x;
    if (e < E) {
        int rel = et[e];
        int key = ei[e] * kRel + rel;
        int old = atomicSub(&cnt[key], 1);
        pcols[rowptr[key] + old - 1] = ei[E + e] | (rel << 26);
    }
}

// fused weights: wallT[r][o][k] = sum_b coef[r,b]*bases[b][k][o]; slot16=selfw^T
__global__ void wall_rg(const void* bases, const void* coef, const void* selfw,
                        const int* dflag, unsigned short* wallT) {
    int idx = blockIdx.x * 256 + threadIdx.x;   // r*16384 + o*128 + k
    int r = idx >> 14;
    int o = (idx >> 7) & 127;
    int k = idx & 127;
    int f = *dflag;
    if (r < kRel) {
        float acc = 0.f;
        for (int b = 0; b < 8; ++b) {
            float cv, bv;
            if (f) {
                cv = ((const float*)coef)[r * 8 + b];
                bv = ((const float*)bases)[b * 16384 + k * 128 + o];
            } else {
                cv = bf2f_rg(((const unsigned short*)coef)[r * 8 + b]);
                bv = bf2f_rg(((const unsigned short*)bases)[b * 16384 + k * 128 + o]);
            }
            acc += cv * bv;
        }
        wallT[idx] = f2bf_rg(acc);
    } else {
        float sv = f ? ((const float*)selfw)[k * 128 + o]
                     : bf2f_rg(((const unsigned short*)selfw)[k * 128 + o]);
        wallT[idx] = f2bf_rg(sv);
    }
}

// aggregate-first: Hall[n][r*128 + o] = mean over r-bucket edges of x[col][o].
// Wave per node (4 waves/block). Buckets contiguous in pcols per (node,rel).
// Per-relation accumulators statically indexed via fully-unrolled r-loop;
// lane-parallel 64-edge chunk prefetch + shfl broadcast (x table is 12.8MB
// bf16 -> gathers served by L2/L3, not HBM).
__global__ __launch_bounds__(256) void agg2_rg(const int* rowptr2, const int* pcols,
                                               const unsigned short* xsrc,
                                               unsigned short* Hall, int N) {
    int wv = threadIdx.x >> 6;
    int lane = threadIdx.x & 63;
    int n = blockIdx.x * 4 + wv;
    if (n >= N) return;
    int bnd = 0;
    if (lane <= kRel) bnd = rowptr2[n * kRel + lane];
    int brv[kRel + 1];
#pragma unroll
    for (int r = 0; r <= kRel; ++r) brv[r] = __shfl(bnd, r);
    const int s = brv[0];
    const int e = brv[kRel];
    int nxt = __shfl(bnd, (lane + 1) & 63);
    float inv = 0.f;
    if (lane < kRel) {
        int d = nxt - bnd;
        inv = (d > 0) ? 1.0f / (float)d : 0.f;
    }
    float a0[kRel], a1[kRel];
#pragma unroll
    for (int r = 0; r < kRel; ++r) { a0[r] = 0.f; a1[r] = 0.f; }
    for (int base = s; base < e; base += 64) {
        int m = e - base;
        if (m > 64) m = 64;
        int pk = 0;
        if (base + lane < e) pk = pcols[base + lane];
#pragma unroll
        for (int r = 0; r < kRel; ++r) {
            int lo = (brv[r] > base) ? brv[r] : base;
            int hi = (brv[r + 1] < base + m) ? brv[r + 1] : (base + m);
            for (int idx = lo; idx < hi; ++idx) {
                int v = __shfl(pk, idx - base);
                int col = v & 0x03FFFFFF;
                unsigned u = *(const unsigned*)(xsrc + (size_t)col * 128 + 2 * lane);
                a0[r] += __uint_as_float(u << 16);
                a1[r] += __uint_as_float(u & 0xffff0000u);
            }
        }
    }
    unsigned short* hrow = Hall + (size_t)n * (kRel * 128) + 2 * lane;
#pragma unroll
    for (int r = 0; r < kRel; ++r) {
        float w = __shfl(inv, r);
        unsigned outp = (unsigned)f2bf_rg(a0[r] * w) | ((unsigned)f2bf_rg(a1[r] * w) << 16);
        *(unsigned*)(hrow + r * 128) = outp;
    }
}

// fused GEMM: out[n][o] = [Hall[n] (K=2048) | x[n] (K=128)] @ wallT[seg][o][k]
// + bias, then LayerNorm + ReLU in-epilogue. 64-row C-tile, 4 waves each
// owning a 64x32 column slice (16x16x32 bf16 MFMA; C map m89/m91:
// col=lane&15, row=(lane>>4)*4+reg). Cross-wave LN via LDS partials.
__global__ __launch_bounds__(256) void fusegemm_rg(const unsigned short* Hall,
                                                   const unsigned short* x,
                                                   const unsigned short* wallT,
                                                   const void* bias, const void* gw,
                                                   const void* bw, const int* dflag,
                                                   unsigned short* out_b, float* out_f,
                                                   int ofp32, int M) {
    __shared__ __align__(16) unsigned short As[64][136];
    __shared__ float pS[64][5];
    __shared__ float pQ[64][5];
    __shared__ float mrs[64][2];
    const int m0 = blockIdx.x * 64;
    const int tid = threadIdx.x;
    const int wave = tid >> 6;
    const int lane = tid & 63;
    const int wn = wave * 32;
    const int lrow = lane & 15;
    const int lq = lane >> 4;
    f32x4 acc[4][2] = {};
    for (int seg = 0; seg < kRel + 1; ++seg) {
        const unsigned short* src;
        size_t rstride;
        if (seg < kRel) { src = Hall + (size_t)seg * 128; rstride = kRel * 128; }
        else            { src = x;                        rstride = 128; }
        __syncthreads();   // protect As against previous segment's readers
        for (int it = 0; it < 4; ++it) {
            int slot = it * 256 + tid;           // 1024 slots = 64 rows x 16 int4
            int row = slot >> 4;
            int c8 = (slot & 15) << 3;
            int gr = m0 + row;
            int4 av = make_int4(0, 0, 0, 0);
            if (gr < M) av = *(const int4*)(src + (size_t)gr * rstride + c8);
            *(int4*)(&As[row][c8]) = av;
        }
        __syncthreads();
        const unsigned short* Bsrc = wallT + (size_t)seg * 16384;
        for (int kk = 0; kk < 128; kk += 32) {
            bf16x8 a[4], b[2];
            int kof = kk + lq * 8;
#pragma unroll
            for (int mt = 0; mt < 4; ++mt)
                a[mt] = *(const bf16x8*)&As[mt * 16 + lrow][kof];
#pragma unroll
            for (int nt = 0; nt < 2; ++nt)
                b[nt] = *(const bf16x8*)(Bsrc + (size_t)(wn + nt * 16 + lrow) * 128 + kof);
#pragma unroll
            for (int mt = 0; mt < 4; ++mt)
#pragma unroll
                for (int nt = 0; nt < 2; ++nt)
                    acc[mt][nt] = __builtin_amdgcn_mfma_f32_16x16x32_bf16(
                        a[mt], b[nt], acc[mt][nt], 0, 0, 0);
        }
    }
    // epilogue: +bias, row mean/var across 128 cols (4 waves x 32 cols), LN+ReLU
    const int f = *dflag;
    float bv[2], gv[2], betav[2];
#pragma unroll
    for (int nt = 0; nt < 2; ++nt) {
        int gc = wn + nt * 16 + lrow;
        if (f) {
            bv[nt] = ((const float*)bias)[gc];
            gv[nt] = ((const float*)gw)[gc];
            betav[nt] = ((const float*)bw)[gc];
        } else {
            bv[nt] = bf2f_rg(((const unsigned short*)bias)[gc]);
            gv[nt] = bf2f_rg(((const unsigned short*)gw)[gc]);
            betav[nt] = bf2f_rg(((const unsigned short*)bw)[gc]);
        }
    }
#pragma unroll
    for (int mt = 0; mt < 4; ++mt)
#pragma unroll
        for (int i = 0; i < 4; ++i) {
            float sv = 0.f, qv = 0.f;
#pragma unroll
            for (int nt = 0; nt < 2; ++nt) {
                float v = acc[mt][nt][i] + bv[nt];
                acc[mt][nt][i] = v;
                sv += v;
                qv += v * v;
            }
            for (int o = 1; o < 16; o <<= 1) {
                sv += __shfl_xor(sv, o);
                qv += __shfl_xor(qv, o);
            }
            if (lrow == 0) {
                int row = mt * 16 + lq * 4 + i;
                pS[row][wave] = sv;
                pQ[row][wave] = qv;
            }
        }
    __syncthreads();
    if (tid < 64) {
        float s4 = pS[tid][0] + pS[tid][1] + pS[tid][2] + pS[tid][3];
        float q4 = pQ[tid][0] + pQ[tid][1] + pQ[tid][2] + pQ[tid][3];
        float mean = s4 * (1.0f / 128.0f);
        float var = q4 * (1.0f / 128.0f) - mean * mean;
        mrs[tid][0] = mean;
        mrs[tid][1] = rsqrtf(var + 1e-5f);
    }
    __syncthreads();
#pragma unroll
    for (int mt = 0; mt < 4; ++mt)
#pragma unroll
        for (int i = 0; i < 4; ++i) {
            int row = mt * 16 + lq * 4 + i;
            int gr = m0 + row;
            if (gr < M) {
                float mean = mrs[row][0];
                float rs = mrs[row][1];
#pragma unroll
                for (int nt = 0; nt < 2; ++nt) {
                    int gc = wn + nt * 16 + lrow;
                    float o = fmaxf((acc[mt][nt][i] - mean) * rs * gv[nt] + betav[nt], 0.f);
                    if (ofp32)
                        out_f[(size_t)gr * 128 + gc] = o;
                    else
                        out_b[(size_t)gr * 128 + gc] = f2bf_rg(o);
                }
            }
        }
}

extern "C" void kernel_launch(void* const* d_in, const int* in_sizes, int n_in,
                              void* d_out, int out_size, void* d_ws, size_t ws_size,
                              hipStream_t stream) {
    const int* ei = (const int*)d_in[0];            // [2,E] int32
    const int* et = (const int*)d_in[1];            // [E] int32
    const void* emb    = d_in[2];
    const void* bases1 = d_in[3];
    const void* coef1  = d_in[4];
    const void* selfw1 = d_in[5];
    const void* bias1  = d_in[6];
    const void* g1     = d_in[7];
    const void* b1     = d_in[8];
    const void* bases2 = d_in[9];
    const void* coef2  = d_in[10];
    const void* selfw2 = d_in[11];
    const void* bias2  = d_in[12];
    const void* g2     = d_in[13];
    const void* b2     = d_in[14];

    const int E = in_sizes[1];
    const int N = out_size / kDim;
    const int n16 = N * kRel;
    const int nsb = (n16 + 255) / 256;

    // workspace (256B-aligned). Hall = [N][2048] bf16 (204.8MB), replaces ygrp.
    char* ws = (char*)d_ws;
    size_t off = 0;
    int* dflag   = (int*)(ws + off); off += 256;
    int* rowptr2 = (int*)(ws + off); off += (((size_t)n16 + 1) * 4 + 255) & ~(size_t)255;
    int* cnt     = (int*)(ws + off); off += ((size_t)n16 * 4 + 255) & ~(size_t)255;
    int* bsum    = (int*)(ws + off); off += ((size_t)nsb * 4 + 255) & ~(size_t)255;
    int* pcols   = (int*)(ws + off); off += ((size_t)E * 4 + 255) & ~(size_t)255;
    unsigned short* wallT = (unsigned short*)(ws + off);
    off += ((size_t)17 * 16384 * 2 + 255) & ~(size_t)255;
    unsigned short* xin  = (unsigned short*)(ws + off);
    off += ((size_t)N * 128 * 2 + 255) & ~(size_t)255;
    unsigned short* xmid = (unsigned short*)(ws + off);
    off += ((size_t)N * 128 * 2 + 255) & ~(size_t)255;
    unsigned short* Hall = (unsigned short*)(ws + off);
    (void)n_in; (void)ws_size;

    const int eblk = (E + 255) / 256;
    const int mblk64 = (N + 63) / 64;
    const int ablk = (N + 3) / 4;
    const int nelem = N * 128;

    // sentinel (template symbol; fully overwritten by fusegemm layer 2)
    RGCNEncoder_89962384982025_kernel<<<(out_size / 2 + 255) / 256, 256, 0, stream>>>(
        (unsigned*)d_out, out_size / 2);

    // dtype detection + emb -> bf16
    detect_rg<<<1, 64, 0, stream>>>((const unsigned short*)emb, dflag);
    cvt_rg<<<(nelem + 255) / 256, 256, 0, stream>>>(emb, dflag, xin, nelem);

    // CSR by (node, relation); in-place hierarchical scan
    zero_rg<<<(n16 + 255) / 256, 256, 0, stream>>>(cnt, n16);
    count_rg<<<eblk, 256, 0, stream>>>(ei, et, cnt, E);
    scanA_rg<<<nsb, 256, 0, stream>>>(cnt, rowptr2, bsum, n16);
    scanB_rg<<<1, 256, 0, stream>>>(bsum, nsb);
    scanC_rg<<<nsb, 256, 0, stream>>>(rowptr2, bsum, n16);
    fill_rg<<<eblk, 256, 0, stream>>>(ei, et, rowptr2, cnt, pcols, E);

    // layer 1: aggregate xin -> Hall, fused GEMM -> bf16 xmid
    wall_rg<<<17 * 64, 256, 0, stream>>>(bases1, coef1, selfw1, dflag, wallT);
    agg2_rg<<<ablk, 256, 0, stream>>>(rowptr2, pcols, xin, Hall, N);
    fusegemm_rg<<<mblk64, 256, 0, stream>>>(Hall, xin, wallT, bias1, g1, b1, dflag,
                                            xmid, (float*)nullptr, 0, N);

    // layer 2: aggregate xmid -> Hall, fused GEMM -> fp32 d_out
    wall_rg<<<17 * 64, 256, 0, stream>>>(bases2, coef2, selfw2, dflag, wallT);
    agg2_rg<<<ablk, 256, 0, stream>>>(rowptr2, pcols, xmid, Hall, N);
    fusegemm_rg<<<mblk64, 256, 0, stream>>>(Hall, xmid, wallT, bias2, g2, b2, dflag,
                                            (unsigned short*)nullptr, (float*)d_out,
                                            1, N);
}

// Round 2
// 518.329 us; speedup vs baseline: 1.0881x; 1.0298x over previous
//
#include <hip/hip_runtime.h>
#include <hip/hip_bf16.h>

// RGCN 2-layer encoder. N=50000, R=16, B=8, Dim=128, E=625000.
// fp32 in/out (runtime-detected), bf16 MFMA internals.
//
// R18: fusegemm pipelined. R17's fusegemm was latency-bound (MfmaUtil 8.9%,
// HBM 12.8%, 17 serial load->barrier->mfma segments). Now: double-buffered
// global_load_lds(16B) A-staging, stage(s+1) issued before compute(s), ONE
// vmcnt(0)+s_barrier per segment (T3 minimum 2-phase recipe); linear LDS
// tile with row-XOR swizzle byte^=((row&7)<<4) applied to BOTH the per-lane
// global source and the ds_read address (rule #21) to kill the 32-way
// bank conflict of the 256B-stride layout.
//
// Pipeline per layer: wallT[r][o][k]=W[r]^T (slot16=selfw^T);
// agg2: wave-per-node CSR scan -> Hall[n][r*128+o] = mean_r(x[col]);
// fusegemm: out[n][o] = [Hall[n] | x[n]] @ wallT (K=2176), epilogue LN+ReLU.

static constexpr int kDim = 128;
static constexpr int kRel = 16;

typedef __attribute__((ext_vector_type(8))) short bf16x8;
typedef __attribute__((ext_vector_type(4))) float f32x4;

static __device__ __forceinline__ float bf2f_rg(unsigned short h) {
    return __uint_as_float(((unsigned)h) << 16);
}
static __device__ __forceinline__ unsigned short f2bf_rg(float f) {
    unsigned u = __float_as_uint(f);
    u = u + 0x7fffu + ((u >> 16) & 1u);   // round-to-nearest-even
    return (unsigned short)(u >> 16);
}

static __device__ __forceinline__ void gload_lds16(const void* g, void* l) {
    __builtin_amdgcn_global_load_lds(
        (const __attribute__((address_space(1))) unsigned*)g,
        (__attribute__((address_space(3))) unsigned*)l, 16, 0, 0);
}

// template-named kernel: sentinel fill (fully overwritten by pipeline)
__global__ void RGCNEncoder_89962384982025_kernel(unsigned* p, int n) {
    int i = blockIdx.x * 256 + threadIdx.x;
    if (i < n) p[i] = 0x3F803F80u;
}

// dtype detection: any bf16-decoded |v|>=128/inf/nan in first 128 halves => fp32
__global__ void detect_rg(const unsigned short* x, int* dflag) {
    if (blockIdx.x == 0 && threadIdx.x == 0) {
        int insane = 0;
        for (int i = 0; i < 128; ++i) {
            unsigned e = ((unsigned)x[i] >> 7) & 0xFFu;
            if (e >= 0x86u) insane = 1;
        }
        *dflag = insane;
    }
}

// convert emb (fp32 or bf16 per flag) -> bf16 xin
__global__ void cvt_rg(const void* xraw, const int* dflag, unsigned short* xout, int n) {
    int i = blockIdx.x * 256 + threadIdx.x;
    if (i >= n) return;
    if (*dflag)
        xout[i] = f2bf_rg(((const float*)xraw)[i]);
    else
        xout[i] = ((const unsigned short*)xraw)[i];
}

__global__ void zero_rg(int* p, int n) {
    int i = blockIdx.x * 256 + threadIdx.x;
    if (i < n) p[i] = 0;
}

__global__ void count_rg(const int* ei, const int* et, int* cnt, int E) {
    int e = blockIdx.x * 256 + threadIdx.x;
    if (e < E) atomicAdd(&cnt[ei[e] * kRel + et[e]], 1);
}

// hierarchical scan, in place on rowptr (saves the incl buffer)
__global__ void scanA_rg(const int* cnt, int* rowptr, int* bsum, int n) {
    __shared__ int sh[256];
    int tid = threadIdx.x;
    int i = blockIdx.x * 256 + tid;
    int v = (i < n) ? cnt[i] : 0;
    sh[tid] = v;
    __syncthreads();
    for (int off = 1; off < 256; off <<= 1) {
        int t = (tid >= off) ? sh[tid - off] : 0;
        __syncthreads();
        sh[tid] += t;
        __syncthreads();
    }
    if (i < n) rowptr[i + 1] = sh[tid];
    if (tid == 255) bsum[blockIdx.x] = sh[255];
}
__global__ void scanB_rg(int* bsum, int nb) {
    __shared__ int partial[256];
    int tid = threadIdx.x;
    int chunk = (nb + 255) / 256;
    int s0 = tid * chunk;
    int s1 = min(s0 + chunk, nb);
    int sum = 0;
    for (int i = s0; i < s1; ++i) sum += bsum[i];
    partial[tid] = sum;
    __syncthreads();
    for (int off = 1; off < 256; off <<= 1) {
        int t = (tid >= off) ? partial[tid - off] : 0;
        __syncthreads();
        partial[tid] += t;
        __syncthreads();
    }
    int run = (tid == 0) ? 0 : partial[tid - 1];
    for (int i = s0; i < s1; ++i) { int v = bsum[i]; bsum[i] = run; run += v; }
}
__global__ void scanC_rg(int* rowptr, const int* bsum, int n) {
    int i = blockIdx.x * 256 + threadIdx.x;
    if (i < n) rowptr[i + 1] += bsum[blockIdx.x];
    if (i == 0) rowptr[0] = 0;
}

// fill: pcols entry packs col | rel<<26 (col < 2^26)
__global__ void fill_rg(const int* ei, const int* et, const int* rowptr,
                        int* cnt, int* pcols, int E) {
    int e = blockIdx.x * 256 + threadIdx.x;
    if (e < E) {
        int rel = et[e];
        int key = ei[e] * kRel + rel;
        int old = atomicSub(&cnt[key], 1);
        pcols[rowptr[key] + old - 1] = ei[E + e] | (rel << 26);
    }
}

// fused weights: wallT[r][o][k] = sum_b coef[r,b]*bases[b][k][o]; slot16=selfw^T
__global__ void wall_rg(const void* bases, const void* coef, const void* selfw,
                        const int* dflag, unsigned short* wallT) {
    int idx = blockIdx.x * 256 + threadIdx.x;   // r*16384 + o*128 + k
    int r = idx >> 14;
    int o = (idx >> 7) & 127;
    int k = idx & 127;
    int f = *dflag;
    if (r < kRel) {
        float acc = 0.f;
        for (int b = 0; b < 8; ++b) {
            float cv, bv;
            if (f) {
                cv = ((const float*)coef)[r * 8 + b];
                bv = ((const float*)bases)[b * 16384 + k * 128 + o];
            } else {
                cv = bf2f_rg(((const unsigned short*)coef)[r * 8 + b]);
                bv = bf2f_rg(((const unsigned short*)bases)[b * 16384 + k * 128 + o]);
            }
            acc += cv * bv;
        }
        wallT[idx] = f2bf_rg(acc);
    } else {
        float sv = f ? ((const float*)selfw)[k * 128 + o]
                     : bf2f_rg(((const unsigned short*)selfw)[k * 128 + o]);
        wallT[idx] = f2bf_rg(sv);
    }
}

// aggregate-first: Hall[n][r*128 + o] = mean over r-bucket edges of x[col][o].
// Wave per node (4 waves/block). Buckets contiguous in pcols per (node,rel).
__global__ __launch_bounds__(256) void agg2_rg(const int* rowptr2, const int* pcols,
                                               const unsigned short* xsrc,
                                               unsigned short* Hall, int N) {
    int wv = threadIdx.x >> 6;
    int lane = threadIdx.x & 63;
    int n = blockIdx.x * 4 + wv;
    if (n >= N) return;
    int bnd = 0;
    if (lane <= kRel) bnd = rowptr2[n * kRel + lane];
    int brv[kRel + 1];
#pragma unroll
    for (int r = 0; r <= kRel; ++r) brv[r] = __shfl(bnd, r);
    const int s = brv[0];
    const int e = brv[kRel];
    int nxt = __shfl(bnd, (lane + 1) & 63);
    float inv = 0.f;
    if (lane < kRel) {
        int d = nxt - bnd;
        inv = (d > 0) ? 1.0f / (float)d : 0.f;
    }
    float a0[kRel], a1[kRel];
#pragma unroll
    for (int r = 0; r < kRel; ++r) { a0[r] = 0.f; a1[r] = 0.f; }
    for (int base = s; base < e; base += 64) {
        int m = e - base;
        if (m > 64) m = 64;
        int pk = 0;
        if (base + lane < e) pk = pcols[base + lane];
#pragma unroll
        for (int r = 0; r < kRel; ++r) {
            int lo = (brv[r] > base) ? brv[r] : base;
            int hi = (brv[r + 1] < base + m) ? brv[r + 1] : (base + m);
            for (int idx = lo; idx < hi; ++idx) {
                int v = __shfl(pk, idx - base);
                int col = v & 0x03FFFFFF;
                unsigned u = *(const unsigned*)(xsrc + (size_t)col * 128 + 2 * lane);
                a0[r] += __uint_as_float(u << 16);
                a1[r] += __uint_as_float(u & 0xffff0000u);
            }
        }
    }
    unsigned short* hrow = Hall + (size_t)n * (kRel * 128) + 2 * lane;
#pragma unroll
    for (int r = 0; r < kRel; ++r) {
        float w = __shfl(inv, r);
        unsigned outp = (unsigned)f2bf_rg(a0[r] * w) | ((unsigned)f2bf_rg(a1[r] * w) << 16);
        *(unsigned*)(hrow + r * 128) = outp;
    }
}

// fused GEMM: out[n][o] = [Hall[n] (K=2048) | x[n] (K=128)] @ wallT[seg][o][k]
// + bias, then LayerNorm + ReLU in-epilogue. 64-row C-tile, 4 waves each
// owning a 64x32 column slice (16x16x32 bf16 MFMA; C map m89/m91:
// col=lane&15, row=(lane>>4)*4+reg). Double-buffered global_load_lds A-tile
// with row-XOR swizzle (both-sides); one vmcnt(0)+s_barrier per segment.
__global__ __launch_bounds__(256, 3) void fusegemm_rg(const unsigned short* Hall,
                                                      const unsigned short* x,
                                                      const unsigned short* wallT,
                                                      const void* bias, const void* gw,
                                                      const void* bw, const int* dflag,
                                                      unsigned short* out_b, float* out_f,
                                                      int ofp32, int M) {
    __shared__ __align__(16) unsigned short As[2][64][128];   // linear, swizzled
    __shared__ float pS[64][5];
    __shared__ float pQ[64][5];
    __shared__ float mrs[64][2];
    const int m0 = blockIdx.x * 64;
    const int tid = threadIdx.x;
    const int wave = tid >> 6;
    const int lane = tid & 63;
    const int wn = wave * 32;
    const int lrow = lane & 15;
    const int lq = lane >> 4;

    // stage segment seg into As[buf]: 4 x global_load_lds(16B) per thread.
    // LDS granule gi=(wave*4+it)*64+lane -> row=gi>>4, slot=gi&15 (linear dest);
    // source within-row byte = slot*16 ^ ((row&7)<<4)  (pre-swizzle, rule #21).
    auto stage = [&](int seg, int buf) {
        const char* srcb;
        size_t rstrideB, segoffB;
        if (seg < kRel) { srcb = (const char*)Hall; rstrideB = 4096; segoffB = (size_t)seg * 256; }
        else            { srcb = (const char*)x;    rstrideB = 256;  segoffB = 0; }
#pragma unroll
        for (int it = 0; it < 4; ++it) {
            int gi = (wave * 4 + it) * 64 + lane;
            int row = gi >> 4;
            int c = ((gi & 15) << 4) ^ ((row & 7) << 4);
            int gr = m0 + row;
            if (gr > M - 1) gr = M - 1;
            const char* src = srcb + (size_t)gr * rstrideB + segoffB + (size_t)c;
            unsigned short* ldst = &As[buf][0][0] + ((wave * 4 + it) << 9);
            gload_lds16(src, ldst);
        }
    };

    f32x4 acc[4][2] = {};
    // prologue: stage segment 0, drain, barrier
    stage(0, 0);
    asm volatile("s_waitcnt vmcnt(0)" ::: "memory");
    __builtin_amdgcn_s_barrier();
    int cur = 0;
    for (int seg = 0; seg < kRel + 1; ++seg) {
        if (seg < kRel) stage(seg + 1, cur ^ 1);
        const unsigned short* Bsrc = wallT + (size_t)seg * 16384;
        bf16x8 a[4][4], b[4][2];
#pragma unroll
        for (int kk4 = 0; kk4 < 4; ++kk4)
#pragma unroll
            for (int nt = 0; nt < 2; ++nt)
                b[kk4][nt] = *(const bf16x8*)(Bsrc + (size_t)(wn + nt * 16 + lrow) * 128
                                              + kk4 * 32 + lq * 8);
#pragma unroll
        for (int kk4 = 0; kk4 < 4; ++kk4)
#pragma unroll
            for (int mt = 0; mt < 4; ++mt) {
                int row = mt * 16 + lrow;
                int cb = (kk4 * 64 + lq * 16) ^ ((row & 7) << 4);
                a[kk4][mt] = *(const bf16x8*)((const char*)&As[cur][0][0]
                                              + row * 256 + cb);
            }
#pragma unroll
        for (int kk4 = 0; kk4 < 4; ++kk4)
#pragma unroll
            for (int mt = 0; mt < 4; ++mt)
#pragma unroll
                for (int nt = 0; nt < 2; ++nt)
                    acc[mt][nt] = __builtin_amdgcn_mfma_f32_16x16x32_bf16(
                        a[kk4][mt], b[kk4][nt], acc[mt][nt], 0, 0, 0);
        asm volatile("s_waitcnt vmcnt(0)" ::: "memory");
        __builtin_amdgcn_s_barrier();
        cur ^= 1;
    }

    // epilogue: +bias, row mean/var across 128 cols (4 waves x 32 cols), LN+ReLU
    const int f = *dflag;
    float bv[2], gv[2], betav[2];
#pragma unroll
    for (int nt = 0; nt < 2; ++nt) {
        int gc = wn + nt * 16 + lrow;
        if (f) {
            bv[nt] = ((const float*)bias)[gc];
            gv[nt] = ((const float*)gw)[gc];
            betav[nt] = ((const float*)bw)[gc];
        } else {
            bv[nt] = bf2f_rg(((const unsigned short*)bias)[gc]);
            gv[nt] = bf2f_rg(((const unsigned short*)gw)[gc]);
            betav[nt] = bf2f_rg(((const unsigned short*)bw)[gc]);
        }
    }
#pragma unroll
    for (int mt = 0; mt < 4; ++mt)
#pragma unroll
        for (int i = 0; i < 4; ++i) {
            float sv = 0.f, qv = 0.f;
#pragma unroll
            for (int nt = 0; nt < 2; ++nt) {
                float v = acc[mt][nt][i] + bv[nt];
                acc[mt][nt][i] = v;
                sv += v;
                qv += v * v;
            }
            for (int o = 1; o < 16; o <<= 1) {
                sv += __shfl_xor(sv, o);
                qv += __shfl_xor(qv, o);
            }
            if (lrow == 0) {
                int row = mt * 16 + lq * 4 + i;
                pS[row][wave] = sv;
                pQ[row][wave] = qv;
            }
        }
    __syncthreads();
    if (tid < 64) {
        float s4 = pS[tid][0] + pS[tid][1] + pS[tid][2] + pS[tid][3];
        float q4 = pQ[tid][0] + pQ[tid][1] + pQ[tid][2] + pQ[tid][3];
        float mean = s4 * (1.0f / 128.0f);
        float var = q4 * (1.0f / 128.0f) - mean * mean;
        mrs[tid][0] = mean;
        mrs[tid][1] = rsqrtf(var + 1e-5f);
    }
    __syncthreads();
#pragma unroll
    for (int mt = 0; mt < 4; ++mt)
#pragma unroll
        for (int i = 0; i < 4; ++i) {
            int row = mt * 16 + lq * 4 + i;
            int gr = m0 + row;
            if (gr < M) {
                float mean = mrs[row][0];
                float rs = mrs[row][1];
#pragma unroll
                for (int nt = 0; nt < 2; ++nt) {
                    int gc = wn + nt * 16 + lrow;
                    float o = fmaxf((acc[mt][nt][i] - mean) * rs * gv[nt] + betav[nt], 0.f);
                    if (ofp32)
                        out_f[(size_t)gr * 128 + gc] = o;
                    else
                        out_b[(size_t)gr * 128 + gc] = f2bf_rg(o);
                }
            }
        }
}

extern "C" void kernel_launch(void* const* d_in, const int* in_sizes, int n_in,
                              void* d_out, int out_size, void* d_ws, size_t ws_size,
                              hipStream_t stream) {
    const int* ei = (const int*)d_in[0];            // [2,E] int32
    const int* et = (const int*)d_in[1];            // [E] int32
    const void* emb    = d_in[2];
    const void* bases1 = d_in[3];
    const void* coef1  = d_in[4];
    const void* selfw1 = d_in[5];
    const void* bias1  = d_in[6];
    const void* g1     = d_in[7];
    const void* b1     = d_in[8];
    const void* bases2 = d_in[9];
    const void* coef2  = d_in[10];
    const void* selfw2 = d_in[11];
    const void* bias2  = d_in[12];
    const void* g2     = d_in[13];
    const void* b2     = d_in[14];

    const int E = in_sizes[1];
    const int N = out_size / kDim;
    const int n16 = N * kRel;
    const int nsb = (n16 + 255) / 256;

    // workspace (256B-aligned). Hall = [N][2048] bf16 (204.8MB).
    char* ws = (char*)d_ws;
    size_t off = 0;
    int* dflag   = (int*)(ws + off); off += 256;
    int* rowptr2 = (int*)(ws + off); off += (((size_t)n16 + 1) * 4 + 255) & ~(size_t)255;
    int* cnt     = (int*)(ws + off); off += ((size_t)n16 * 4 + 255) & ~(size_t)255;
    int* bsum    = (int*)(ws + off); off += ((size_t)nsb * 4 + 255) & ~(size_t)255;
    int* pcols   = (int*)(ws + off); off += ((size_t)E * 4 + 255) & ~(size_t)255;
    unsigned short* wallT = (unsigned short*)(ws + off);
    off += ((size_t)17 * 16384 * 2 + 255) & ~(size_t)255;
    unsigned short* xin  = (unsigned short*)(ws + off);
    off += ((size_t)N * 128 * 2 + 255) & ~(size_t)255;
    unsigned short* xmid = (unsigned short*)(ws + off);
    off += ((size_t)N * 128 * 2 + 255) & ~(size_t)255;
    unsigned short* Hall = (unsigned short*)(ws + off);
    (void)n_in; (void)ws_size;

    const int eblk = (E + 255) / 256;
    const int mblk64 = (N + 63) / 64;
    const int ablk = (N + 3) / 4;
    const int nelem = N * 128;

    // sentinel (template symbol; fully overwritten by fusegemm layer 2)
    RGCNEncoder_89962384982025_kernel<<<(out_size / 2 + 255) / 256, 256, 0, stream>>>(
        (unsigned*)d_out, out_size / 2);

    // dtype detection + emb -> bf16
    detect_rg<<<1, 64, 0, stream>>>((const unsigned short*)emb, dflag);
    cvt_rg<<<(nelem + 255) / 256, 256, 0, stream>>>(emb, dflag, xin, nelem);

    // CSR by (node, relation); in-place hierarchical scan
    zero_rg<<<(n16 + 255) / 256, 256, 0, stream>>>(cnt, n16);
    count_rg<<<eblk, 256, 0, stream>>>(ei, et, cnt, E);
    scanA_rg<<<nsb, 256, 0, stream>>>(cnt, rowptr2, bsum, n16);
    scanB_rg<<<1, 256, 0, stream>>>(bsum, nsb);
    scanC_rg<<<nsb, 256, 0, stream>>>(rowptr2, bsum, n16);
    fill_rg<<<eblk, 256, 0, stream>>>(ei, et, rowptr2, cnt, pcols, E);

    // layer 1: aggregate xin -> Hall, fused GEMM -> bf16 xmid
    wall_rg<<<17 * 64, 256, 0, stream>>>(bases1, coef1, selfw1, dflag, wallT);
    agg2_rg<<<ablk, 256, 0, stream>>>(rowptr2, pcols, xin, Hall, N);
    fusegemm_rg<<<mblk64, 256, 0, stream>>>(Hall, xin, wallT, bias1, g1, b1, dflag,
                                            xmid, (float*)nullptr, 0, N);

    // layer 2: aggregate xmid -> Hall, fused GEMM -> fp32 d_out
    wall_rg<<<17 * 64, 256, 0, stream>>>(bases2, coef2, selfw2, dflag, wallT);
    agg2_rg<<<ablk, 256, 0, stream>>>(rowptr2, pcols, xmid, Hall, N);
    fusegemm_rg<<<mblk64, 256, 0, stream>>>(Hall, xmid, wallT, bias2, g2, b2, dflag,
                                            (unsigned short*)nullptr, (float*)d_out,
                                            1, N);
}

// Round 4
// 423.095 us; speedup vs baseline: 1.3331x; 1.2251x over previous
//
#include <hip/hip_runtime.h>
#include <hip/hip_bf16.h>

// RGCN 2-layer encoder. N=50000, R=16, B=8, Dim=128, E=625000.
// fp32 in/out (runtime-detected), bf16 MFMA internals.
//
// R19b: basis-space mixing (R19 + compile fix: layer-2 agg2_rg call was
// missing coefw). W_r = sum_b c_rb B_b commutes with the per-rel mean, so
// agg emits 8 basis-aggregates G_b = sum_r c_rb * mean_r(x) instead of 16
// relation means: Gall = 102MB (was Hall 205MB), fused GEMM K=1152
// (9 segments, was 2176/17). Mix cost: 16 FMA + 1 shfl per nonempty bucket
// with uniform-address coef loads (coef pre-decoded fp32 by wall_rg).
// fusegemm pipeline ordering fixed: B-loads issued BEFORE stage(seg+1)
// (vmcnt completes oldest-first; R18's b-after-stage forced a full drain
// of the prefetch before every MFMA block). sched_barrier(0) pins order.
//
// Pipeline per layer: wallT[b][o][k]=bases[b]^T (slot8=selfw^T) + coefw fp32;
// agg2: wave-per-node CSR scan -> Gall[n][b*128+o];
// fusegemm: out[n][o] = [Gall[n] | x[n]] @ wallT (K=1152), epilogue LN+ReLU.

static constexpr int kDim = 128;
static constexpr int kRel = 16;
static constexpr int kBas = 8;
static constexpr int kSeg = kBas + 1;   // 8 bases + self

typedef __attribute__((ext_vector_type(8))) short bf16x8;
typedef __attribute__((ext_vector_type(4))) float f32x4;

static __device__ __forceinline__ float bf2f_rg(unsigned short h) {
    return __uint_as_float(((unsigned)h) << 16);
}
static __device__ __forceinline__ unsigned short f2bf_rg(float f) {
    unsigned u = __float_as_uint(f);
    u = u + 0x7fffu + ((u >> 16) & 1u);   // round-to-nearest-even
    return (unsigned short)(u >> 16);
}

static __device__ __forceinline__ void gload_lds16(const void* g, void* l) {
    __builtin_amdgcn_global_load_lds(
        (const __attribute__((address_space(1))) unsigned*)g,
        (__attribute__((address_space(3))) unsigned*)l, 16, 0, 0);
}

// template-named kernel: sentinel fill (fully overwritten by pipeline)
__global__ void RGCNEncoder_89962384982025_kernel(unsigned* p, int n) {
    int i = blockIdx.x * 256 + threadIdx.x;
    if (i < n) p[i] = 0x3F803F80u;
}

// dtype detection: any bf16-decoded |v|>=128/inf/nan in first 128 halves => fp32
__global__ void detect_rg(const unsigned short* x, int* dflag) {
    if (blockIdx.x == 0 && threadIdx.x == 0) {
        int insane = 0;
        for (int i = 0; i < 128; ++i) {
            unsigned e = ((unsigned)x[i] >> 7) & 0xFFu;
            if (e >= 0x86u) insane = 1;
        }
        *dflag = insane;
    }
}

// convert emb (fp32 or bf16 per flag) -> bf16 xin
__global__ void cvt_rg(const void* xraw, const int* dflag, unsigned short* xout, int n) {
    int i = blockIdx.x * 256 + threadIdx.x;
    if (i >= n) return;
    if (*dflag)
        xout[i] = f2bf_rg(((const float*)xraw)[i]);
    else
        xout[i] = ((const unsigned short*)xraw)[i];
}

__global__ void zero_rg(int* p, int n) {
    int i = blockIdx.x * 256 + threadIdx.x;
    if (i < n) p[i] = 0;
}

__global__ void count_rg(const int* ei, const int* et, int* cnt, int E) {
    int e = blockIdx.x * 256 + threadIdx.x;
    if (e < E) atomicAdd(&cnt[ei[e] * kRel + et[e]], 1);
}

// hierarchical scan, in place on rowptr (saves the incl buffer)
__global__ void scanA_rg(const int* cnt, int* rowptr, int* bsum, int n) {
    __shared__ int sh[256];
    int tid = threadIdx.x;
    int i = blockIdx.x * 256 + tid;
    int v = (i < n) ? cnt[i] : 0;
    sh[tid] = v;
    __syncthreads();
    for (int off = 1; off < 256; off <<= 1) {
        int t = (tid >= off) ? sh[tid - off] : 0;
        __syncthreads();
        sh[tid] += t;
        __syncthreads();
    }
    if (i < n) rowptr[i + 1] = sh[tid];
    if (tid == 255) bsum[blockIdx.x] = sh[255];
}
__global__ void scanB_rg(int* bsum, int nb) {
    __shared__ int partial[256];
    int tid = threadIdx.x;
    int chunk = (nb + 255) / 256;
    int s0 = tid * chunk;
    int s1 = min(s0 + chunk, nb);
    int sum = 0;
    for (int i = s0; i < s1; ++i) sum += bsum[i];
    partial[tid] = sum;
    __syncthreads();
    for (int off = 1; off < 256; off <<= 1) {
        int t = (tid >= off) ? partial[tid - off] : 0;
        __syncthreads();
        partial[tid] += t;
        __syncthreads();
    }
    int run = (tid == 0) ? 0 : partial[tid - 1];
    for (int i = s0; i < s1; ++i) { int v = bsum[i]; bsum[i] = run; run += v; }
}
__global__ void scanC_rg(int* rowptr, const int* bsum, int n) {
    int i = blockIdx.x * 256 + threadIdx.x;
    if (i < n) rowptr[i + 1] += bsum[blockIdx.x];
    if (i == 0) rowptr[0] = 0;
}

// fill: pcols entry packs col | rel<<26 (col < 2^26)
__global__ void fill_rg(const int* ei, const int* et, const int* rowptr,
                        int* cnt, int* pcols, int E) {
    int e = blockIdx.x * 256 + threadIdx.x;
    if (e < E) {
        int rel = et[e];
        int key = ei[e] * kRel + rel;
        int old = atomicSub(&cnt[key], 1);
        pcols[rowptr[key] + old - 1] = ei[E + e] | (rel << 26);
    }
}

// wallT[b][o][k] = bases[b][k][o] for b<8; slot 8 = selfw^T.
// Also stages coef decoded to fp32 (coefw[16][8]) for agg2's uniform loads.
__global__ void wall_rg(const void* bases, const void* coef, const void* selfw,
                        const int* dflag, unsigned short* wallT, float* coefw) {
    int idx = blockIdx.x * 256 + threadIdx.x;   // b*16384 + o*128 + k
    int b = idx >> 14;
    int o = (idx >> 7) & 127;
    int k = idx & 127;
    int f = *dflag;
    if (blockIdx.x == 0 && threadIdx.x < kRel * kBas) {
        coefw[threadIdx.x] = f ? ((const float*)coef)[threadIdx.x]
                               : bf2f_rg(((const unsigned short*)coef)[threadIdx.x]);
    }
    if (b < kBas) {
        float bv = f ? ((const float*)bases)[b * 16384 + k * 128 + o]
                     : bf2f_rg(((const unsigned short*)bases)[b * 16384 + k * 128 + o]);
        wallT[idx] = f2bf_rg(bv);
    } else {
        float sv = f ? ((const float*)selfw)[k * 128 + o]
                     : bf2f_rg(((const unsigned short*)selfw)[k * 128 + o]);
        wallT[idx] = f2bf_rg(sv);
    }
}

// aggregate-first in basis space: Gall[n][b*128+o] = sum_r coefw[r][b] *
// mean over r-bucket edges of x[col][o]. Wave per node (4 waves/block).
// Buckets contiguous in pcols per (node,rel); per-bucket plain sums s0,s1
// mixed into g[8] at bucket end (16 FMA w/ uniform-address coef loads).
__global__ __launch_bounds__(256) void agg2_rg(const int* rowptr2, const int* pcols,
                                               const unsigned short* xsrc,
                                               const float* coefw,
                                               unsigned short* Gall, int N) {
    int wv = threadIdx.x >> 6;
    int lane = threadIdx.x & 63;
    int n = blockIdx.x * 4 + wv;
    if (n >= N) return;
    int bnd = 0;
    if (lane <= kRel) bnd = rowptr2[n * kRel + lane];
    int brv[kRel + 1];
#pragma unroll
    for (int r = 0; r <= kRel; ++r) brv[r] = __shfl(bnd, r);
    const int s = brv[0];
    const int e = brv[kRel];
    int nxt = __shfl(bnd, (lane + 1) & 63);
    float inv = 0.f;
    if (lane < kRel) {
        int d = nxt - bnd;
        inv = (d > 0) ? 1.0f / (float)d : 0.f;
    }
    float g0[kBas], g1[kBas];
#pragma unroll
    for (int b = 0; b < kBas; ++b) { g0[b] = 0.f; g1[b] = 0.f; }
    float s0 = 0.f, s1 = 0.f;
    for (int base = s; base < e; base += 64) {
        int m = e - base;
        if (m > 64) m = 64;
        int pk = 0;
        if (base + lane < e) pk = pcols[base + lane];
#pragma unroll
        for (int r = 0; r < kRel; ++r) {
            int lo = (brv[r] > base) ? brv[r] : base;
            int hi = (brv[r + 1] < base + m) ? brv[r + 1] : (base + m);
            for (int idx = lo; idx < hi; ++idx) {
                int v = __shfl(pk, idx - base);
                int col = v & 0x03FFFFFF;
                unsigned u = *(const unsigned*)(xsrc + (size_t)col * 128 + 2 * lane);
                s0 += __uint_as_float(u << 16);
                s1 += __uint_as_float(u & 0xffff0000u);
            }
            // bucket r ends inside this chunk and is nonempty -> mix into g
            if (brv[r + 1] > base && brv[r + 1] <= base + m && brv[r + 1] > brv[r]) {
                float w = __shfl(inv, r);
                float t0 = s0 * w, t1 = s1 * w;
#pragma unroll
                for (int b = 0; b < kBas; ++b) {
                    float c = coefw[r * kBas + b];   // uniform addr -> scalar load
                    g0[b] += c * t0;
                    g1[b] += c * t1;
                }
                s0 = 0.f; s1 = 0.f;
            }
        }
    }
    unsigned short* grow = Gall + (size_t)n * (kBas * 128) + 2 * lane;
#pragma unroll
    for (int b = 0; b < kBas; ++b) {
        unsigned outp = (unsigned)f2bf_rg(g0[b]) | ((unsigned)f2bf_rg(g1[b]) << 16);
        *(unsigned*)(grow + b * 128) = outp;
    }
}

// fused GEMM: out[n][o] = [Gall[n] (K=1024) | x[n] (K=128)] @ wallT[seg][o][k]
// + bias, then LayerNorm + ReLU in-epilogue. 64-row C-tile, 4 waves each
// owning a 64x32 column slice (16x16x32 bf16 MFMA; C map m89/m91:
// col=lane&15, row=(lane>>4)*4+reg). Double-buffered global_load_lds A-tile
// with row-XOR swizzle (both-sides); per segment: B-loads FIRST, then
// stage(seg+1), then quadrant-wise ds_read+MFMA, then vmcnt(0)+barrier.
__global__ __launch_bounds__(256, 3) void fusegemm_rg(const unsigned short* Gall,
                                                      const unsigned short* x,
                                                      const unsigned short* wallT,
                                                      const void* bias, const void* gw,
                                                      const void* bw, const int* dflag,
                                                      unsigned short* out_b, float* out_f,
                                                      int ofp32, int M) {
    __shared__ __align__(16) unsigned short As[2][64][128];   // linear, swizzled
    __shared__ float pS[64][5];
    __shared__ float pQ[64][5];
    __shared__ float mrs[64][2];
    const int m0 = blockIdx.x * 64;
    const int tid = threadIdx.x;
    const int wave = tid >> 6;
    const int lane = tid & 63;
    const int wn = wave * 32;
    const int lrow = lane & 15;
    const int lq = lane >> 4;

    // stage segment seg into As[buf]: 4 x global_load_lds(16B) per thread.
    // LDS granule gi=(wave*4+it)*64+lane -> row=gi>>4, slot=gi&15 (linear dest);
    // source within-row byte = slot*16 ^ ((row&7)<<4)  (pre-swizzle, rule #21).
    auto stage = [&](int seg, int buf) {
        const char* srcb;
        size_t rstrideB, segoffB;
        if (seg < kBas) { srcb = (const char*)Gall; rstrideB = kBas * 256; segoffB = (size_t)seg * 256; }
        else            { srcb = (const char*)x;    rstrideB = 256;        segoffB = 0; }
#pragma unroll
        for (int it = 0; it < 4; ++it) {
            int gi = (wave * 4 + it) * 64 + lane;
            int row = gi >> 4;
            int c = ((gi & 15) << 4) ^ ((row & 7) << 4);
            int gr = m0 + row;
            if (gr > M - 1) gr = M - 1;
            const char* src = srcb + (size_t)gr * rstrideB + segoffB + (size_t)c;
            unsigned short* ldst = &As[buf][0][0] + ((wave * 4 + it) << 9);
            gload_lds16(src, ldst);
        }
    };

    f32x4 acc[4][2] = {};
    // prologue: stage segment 0, drain, barrier
    stage(0, 0);
    asm volatile("s_waitcnt vmcnt(0)" ::: "memory");
    __builtin_amdgcn_s_barrier();
    int cur = 0;
    for (int seg = 0; seg < kSeg; ++seg) {
        // B-loads FIRST (oldest in vmcnt queue -> their wait doesn't drain stage)
        const unsigned short* Bsrc = wallT + (size_t)seg * 16384;
        bf16x8 b[4][2];
#pragma unroll
        for (int kk4 = 0; kk4 < 4; ++kk4)
#pragma unroll
            for (int nt = 0; nt < 2; ++nt)
                b[kk4][nt] = *(const bf16x8*)(Bsrc + (size_t)(wn + nt * 16 + lrow) * 128
                                              + kk4 * 32 + lq * 8);
        __builtin_amdgcn_sched_barrier(0);   // pin: b-loads issue before stage
        if (seg < kSeg - 1) stage(seg + 1, cur ^ 1);
#pragma unroll
        for (int kk4 = 0; kk4 < 4; ++kk4) {
            bf16x8 a4[4];
#pragma unroll
            for (int mt = 0; mt < 4; ++mt) {
                int row = mt * 16 + lrow;
                int cb = (kk4 * 64 + lq * 16) ^ ((row & 7) << 4);
                a4[mt] = *(const bf16x8*)((const char*)&As[cur][0][0]
                                          + row * 256 + cb);
            }
#pragma unroll
            for (int mt = 0; mt < 4; ++mt)
#pragma unroll
                for (int nt = 0; nt < 2; ++nt)
                    acc[mt][nt] = __builtin_amdgcn_mfma_f32_16x16x32_bf16(
                        a4[mt], b[kk4][nt], acc[mt][nt], 0, 0, 0);
        }
        asm volatile("s_waitcnt vmcnt(0)" ::: "memory");
        __builtin_amdgcn_s_barrier();
        cur ^= 1;
    }

    // epilogue: +bias, row mean/var across 128 cols (4 waves x 32 cols), LN+ReLU
    const int f = *dflag;
    float bv[2], gv[2], betav[2];
#pragma unroll
    for (int nt = 0; nt < 2; ++nt) {
        int gc = wn + nt * 16 + lrow;
        if (f) {
            bv[nt] = ((const float*)bias)[gc];
            gv[nt] = ((const float*)gw)[gc];
            betav[nt] = ((const float*)bw)[gc];
        } else {
            bv[nt] = bf2f_rg(((const unsigned short*)bias)[gc]);
            gv[nt] = bf2f_rg(((const unsigned short*)gw)[gc]);
            betav[nt] = bf2f_rg(((const unsigned short*)bw)[gc]);
        }
    }
#pragma unroll
    for (int mt = 0; mt < 4; ++mt)
#pragma unroll
        for (int i = 0; i < 4; ++i) {
            float sv = 0.f, qv = 0.f;
#pragma unroll
            for (int nt = 0; nt < 2; ++nt) {
                float v = acc[mt][nt][i] + bv[nt];
                acc[mt][nt][i] = v;
                sv += v;
                qv += v * v;
            }
            for (int o = 1; o < 16; o <<= 1) {
                sv += __shfl_xor(sv, o);
                qv += __shfl_xor(qv, o);
            }
            if (lrow == 0) {
                int row = mt * 16 + lq * 4 + i;
                pS[row][wave] = sv;
                pQ[row][wave] = qv;
            }
        }
    __syncthreads();
    if (tid < 64) {
        float s4 = pS[tid][0] + pS[tid][1] + pS[tid][2] + pS[tid][3];
        float q4 = pQ[tid][0] + pQ[tid][1] + pQ[tid][2] + pQ[tid][3];
        float mean = s4 * (1.0f / 128.0f);
        float var = q4 * (1.0f / 128.0f) - mean * mean;
        mrs[tid][0] = mean;
        mrs[tid][1] = rsqrtf(var + 1e-5f);
    }
    __syncthreads();
#pragma unroll
    for (int mt = 0; mt < 4; ++mt)
#pragma unroll
        for (int i = 0; i < 4; ++i) {
            int row = mt * 16 + lq * 4 + i;
            int gr = m0 + row;
            if (gr < M) {
                float mean = mrs[row][0];
                float rs = mrs[row][1];
#pragma unroll
                for (int nt = 0; nt < 2; ++nt) {
                    int gc = wn + nt * 16 + lrow;
                    float o = fmaxf((acc[mt][nt][i] - mean) * rs * gv[nt] + betav[nt], 0.f);
                    if (ofp32)
                        out_f[(size_t)gr * 128 + gc] = o;
                    else
                        out_b[(size_t)gr * 128 + gc] = f2bf_rg(o);
                }
            }
        }
}

extern "C" void kernel_launch(void* const* d_in, const int* in_sizes, int n_in,
                              void* d_out, int out_size, void* d_ws, size_t ws_size,
                              hipStream_t stream) {
    const int* ei = (const int*)d_in[0];            // [2,E] int32
    const int* et = (const int*)d_in[1];            // [E] int32
    const void* emb    = d_in[2];
    const void* bases1 = d_in[3];
    const void* coef1  = d_in[4];
    const void* selfw1 = d_in[5];
    const void* bias1  = d_in[6];
    const void* g1     = d_in[7];
    const void* b1     = d_in[8];
    const void* bases2 = d_in[9];
    const void* coef2  = d_in[10];
    const void* selfw2 = d_in[11];
    const void* bias2  = d_in[12];
    const void* g2     = d_in[13];
    const void* b2     = d_in[14];

    const int E = in_sizes[1];
    const int N = out_size / kDim;
    const int n16 = N * kRel;
    const int nsb = (n16 + 255) / 256;

    // workspace (256B-aligned). Gall = [N][1024] bf16 (102.4MB).
    char* ws = (char*)d_ws;
    size_t off = 0;
    int* dflag   = (int*)(ws + off); off += 256;
    float* coefw = (float*)(ws + off); off += 512;
    int* rowptr2 = (int*)(ws + off); off += (((size_t)n16 + 1) * 4 + 255) & ~(size_t)255;
    int* cnt     = (int*)(ws + off); off += ((size_t)n16 * 4 + 255) & ~(size_t)255;
    int* bsum    = (int*)(ws + off); off += ((size_t)nsb * 4 + 255) & ~(size_t)255;
    int* pcols   = (int*)(ws + off); off += ((size_t)E * 4 + 255) & ~(size_t)255;
    unsigned short* wallT = (unsigned short*)(ws + off);
    off += ((size_t)kSeg * 16384 * 2 + 255) & ~(size_t)255;
    unsigned short* xin  = (unsigned short*)(ws + off);
    off += ((size_t)N * 128 * 2 + 255) & ~(size_t)255;
    unsigned short* xmid = (unsigned short*)(ws + off);
    off += ((size_t)N * 128 * 2 + 255) & ~(size_t)255;
    unsigned short* Gall = (unsigned short*)(ws + off);
    (void)n_in; (void)ws_size;

    const int eblk = (E + 255) / 256;
    const int mblk64 = (N + 63) / 64;
    const int ablk = (N + 3) / 4;
    const int nelem = N * 128;

    // sentinel (template symbol; fully overwritten by fusegemm layer 2)
    RGCNEncoder_89962384982025_kernel<<<(out_size / 2 + 255) / 256, 256, 0, stream>>>(
        (unsigned*)d_out, out_size / 2);

    // dtype detection + emb -> bf16
    detect_rg<<<1, 64, 0, stream>>>((const unsigned short*)emb, dflag);
    cvt_rg<<<(nelem + 255) / 256, 256, 0, stream>>>(emb, dflag, xin, nelem);

    // CSR by (node, relation); in-place hierarchical scan
    zero_rg<<<(n16 + 255) / 256, 256, 0, stream>>>(cnt, n16);
    count_rg<<<eblk, 256, 0, stream>>>(ei, et, cnt, E);
    scanA_rg<<<nsb, 256, 0, stream>>>(cnt, rowptr2, bsum, n16);
    scanB_rg<<<1, 256, 0, stream>>>(bsum, nsb);
    scanC_rg<<<nsb, 256, 0, stream>>>(rowptr2, bsum, n16);
    fill_rg<<<eblk, 256, 0, stream>>>(ei, et, rowptr2, cnt, pcols, E);

    // layer 1: aggregate xin -> Gall (basis space), fused GEMM -> bf16 xmid
    wall_rg<<<kSeg * 64, 256, 0, stream>>>(bases1, coef1, selfw1, dflag, wallT, coefw);
    agg2_rg<<<ablk, 256, 0, stream>>>(rowptr2, pcols, xin, coefw, Gall, N);
    fusegemm_rg<<<mblk64, 256, 0, stream>>>(Gall, xin, wallT, bias1, g1, b1, dflag,
                                            xmid, (float*)nullptr, 0, N);

    // layer 2: aggregate xmid -> Gall, fused GEMM -> fp32 d_out
    wall_rg<<<kSeg * 64, 256, 0, stream>>>(bases2, coef2, selfw2, dflag, wallT, coefw);
    agg2_rg<<<ablk, 256, 0, stream>>>(rowptr2, pcols, xmid, coefw, Gall, N);
    fusegemm_rg<<<mblk64, 256, 0, stream>>>(Gall, xmid, wallT, bias2, g2, b2, dflag,
                                            (unsigned short*)nullptr, (float*)d_out,
                                            1, N);
}

// Round 5
// 413.337 us; speedup vs baseline: 1.3645x; 1.0236x over previous
//
#include <hip/hip_runtime.h>
#include <hip/hip_bf16.h>

// RGCN 2-layer encoder. N=50000, R=16, B=8, Dim=128, E=625000.
// fp32 in/out (runtime-detected), bf16 MFMA internals.
//
// R20: agg2 VALU diet. R19's agg2 was VALU-bound (58% VALUBusy): per-chunk
// 16-relation bounds scaffold + shfl broadcast + per-bucket inv-shfl cost
// ~550 VALU/node/lane. Rewritten as a relation-transition loop driven by
// v_readlane (uniform loop counter -> SGPR): rel extract/compare/branch and
// column addressing move to SALU; bucket size counted on the fly with
// v_rcp_f32 at transitions; coefs in LDS (broadcast ds_read). Per-edge VALU
// = 4 (2 unpack + 2 add); mix (16 FMA/bucket) now dominates = the
// irreducible RxBxD basis-projection cost. detect_rg parallelized.
//
// Pipeline per layer: wallT[b][o][k]=bases[b]^T (slot8=selfw^T) + coefw fp32;
// agg2: wave-per-node CSR scan -> Gall[n][b*128+o] (basis space, 102MB);
// fusegemm: out[n][o] = [Gall[n] | x[n]] @ wallT (K=1152), epilogue LN+ReLU.

static constexpr int kDim = 128;
static constexpr int kRel = 16;
static constexpr int kBas = 8;
static constexpr int kSeg = kBas + 1;   // 8 bases + self

typedef __attribute__((ext_vector_type(8))) short bf16x8;
typedef __attribute__((ext_vector_type(4))) float f32x4;

static __device__ __forceinline__ float bf2f_rg(unsigned short h) {
    return __uint_as_float(((unsigned)h) << 16);
}
static __device__ __forceinline__ unsigned short f2bf_rg(float f) {
    unsigned u = __float_as_uint(f);
    u = u + 0x7fffu + ((u >> 16) & 1u);   // round-to-nearest-even
    return (unsigned short)(u >> 16);
}

static __device__ __forceinline__ void gload_lds16(const void* g, void* l) {
    __builtin_amdgcn_global_load_lds(
        (const __attribute__((address_space(1))) unsigned*)g,
        (__attribute__((address_space(3))) unsigned*)l, 16, 0, 0);
}

// template-named kernel: sentinel fill (fully overwritten by pipeline)
__global__ void RGCNEncoder_89962384982025_kernel(unsigned* p, int n) {
    int i = blockIdx.x * 256 + threadIdx.x;
    if (i < n) p[i] = 0x3F803F80u;
}

// dtype detection: any bf16-decoded |v|>=128/inf/nan in first 128 halves => fp32
__global__ void detect_rg(const unsigned short* x, int* dflag) {
    if (blockIdx.x == 0 && threadIdx.x < 64) {
        int t = threadIdx.x;
        unsigned e0 = ((unsigned)x[t] >> 7) & 0xFFu;
        unsigned e1 = ((unsigned)x[t + 64] >> 7) & 0xFFu;
        int bad = (e0 >= 0x86u) || (e1 >= 0x86u);
        unsigned long long m = __ballot(bad);
        if (t == 0) *dflag = (m != 0ull) ? 1 : 0;
    }
}

// convert emb (fp32 or bf16 per flag) -> bf16 xin
__global__ void cvt_rg(const void* xraw, const int* dflag, unsigned short* xout, int n) {
    int i = blockIdx.x * 256 + threadIdx.x;
    if (i >= n) return;
    if (*dflag)
        xout[i] = f2bf_rg(((const float*)xraw)[i]);
    else
        xout[i] = ((const unsigned short*)xraw)[i];
}

__global__ void zero_rg(int* p, int n) {
    int i = blockIdx.x * 256 + threadIdx.x;
    if (i < n) p[i] = 0;
}

__global__ void count_rg(const int* ei, const int* et, int* cnt, int E) {
    int e = blockIdx.x * 256 + threadIdx.x;
    if (e < E) atomicAdd(&cnt[ei[e] * kRel + et[e]], 1);
}

// hierarchical scan, in place on rowptr (saves the incl buffer)
__global__ void scanA_rg(const int* cnt, int* rowptr, int* bsum, int n) {
    __shared__ int sh[256];
    int tid = threadIdx.x;
    int i = blockIdx.x * 256 + tid;
    int v = (i < n) ? cnt[i] : 0;
    sh[tid] = v;
    __syncthreads();
    for (int off = 1; off < 256; off <<= 1) {
        int t = (tid >= off) ? sh[tid - off] : 0;
        __syncthreads();
        sh[tid] += t;
        __syncthreads();
    }
    if (i < n) rowptr[i + 1] = sh[tid];
    if (tid == 255) bsum[blockIdx.x] = sh[255];
}
__global__ void scanB_rg(int* bsum, int nb) {
    __shared__ int partial[256];
    int tid = threadIdx.x;
    int chunk = (nb + 255) / 256;
    int s0 = tid * chunk;
    int s1 = min(s0 + chunk, nb);
    int sum = 0;
    for (int i = s0; i < s1; ++i) sum += bsum[i];
    partial[tid] = sum;
    __syncthreads();
    for (int off = 1; off < 256; off <<= 1) {
        int t = (tid >= off) ? partial[tid - off] : 0;
        __syncthreads();
        partial[tid] += t;
        __syncthreads();
    }
    int run = (tid == 0) ? 0 : partial[tid - 1];
    for (int i = s0; i < s1; ++i) { int v = bsum[i]; bsum[i] = run; run += v; }
}
__global__ void scanC_rg(int* rowptr, const int* bsum, int n) {
    int i = blockIdx.x * 256 + threadIdx.x;
    if (i < n) rowptr[i + 1] += bsum[blockIdx.x];
    if (i == 0) rowptr[0] = 0;
}

// fill: pcols entry packs col | rel<<26 (col < 2^26)
__global__ void fill_rg(const int* ei, const int* et, const int* rowptr,
                        int* cnt, int* pcols, int E) {
    int e = blockIdx.x * 256 + threadIdx.x;
    if (e < E) {
        int rel = et[e];
        int key = ei[e] * kRel + rel;
        int old = atomicSub(&cnt[key], 1);
        pcols[rowptr[key] + old - 1] = ei[E + e] | (rel << 26);
    }
}

// wallT[b][o][k] = bases[b][k][o] for b<8; slot 8 = selfw^T.
// Also stages coef decoded to fp32 (coefw[16][8]) for agg2's LDS mix table.
__global__ void wall_rg(const void* bases, const void* coef, const void* selfw,
                        const int* dflag, unsigned short* wallT, float* coefw) {
    int idx = blockIdx.x * 256 + threadIdx.x;   // b*16384 + o*128 + k
    int b = idx >> 14;
    int o = (idx >> 7) & 127;
    int k = idx & 127;
    int f = *dflag;
    if (blockIdx.x == 0 && threadIdx.x < kRel * kBas) {
        coefw[threadIdx.x] = f ? ((const float*)coef)[threadIdx.x]
                               : bf2f_rg(((const unsigned short*)coef)[threadIdx.x]);
    }
    if (b < kBas) {
        float bv = f ? ((const float*)bases)[b * 16384 + k * 128 + o]
                     : bf2f_rg(((const unsigned short*)bases)[b * 16384 + k * 128 + o]);
        wallT[idx] = f2bf_rg(bv);
    } else {
        float sv = f ? ((const float*)selfw)[k * 128 + o]
                     : bf2f_rg(((const unsigned short*)selfw)[k * 128 + o]);
        wallT[idx] = f2bf_rg(sv);
    }
}

// aggregate-first in basis space: Gall[n][b*128+o] = sum_r coefw[r][b] *
// mean over r-bucket edges of x[col][o]. Wave per node (4 waves/block).
// Relation-transition loop: per-chunk lane-parallel pcols prefetch, then
// v_readlane (SGPR) per edge -> rel/col on the scalar pipe; bucket size
// counted on the fly, rcp at transition; coef mix from LDS broadcast.
__global__ __launch_bounds__(256) void agg2_rg(const int* rowptr2, const int* pcols,
                                               const unsigned short* xsrc,
                                               const float* coefw,
                                               unsigned short* Gall, int N) {
    __shared__ float csh[kRel * kBas];
    if (threadIdx.x < kRel * kBas) csh[threadIdx.x] = coefw[threadIdx.x];
    __syncthreads();
    int wv = threadIdx.x >> 6;
    int lane = threadIdx.x & 63;
    int n = blockIdx.x * 4 + wv;
    if (n >= N) return;
    const int s = rowptr2[n * kRel];          // wave-uniform -> scalar load
    const int e = rowptr2[n * kRel + kRel];
    float g0[kBas], g1[kBas];
#pragma unroll
    for (int b = 0; b < kBas; ++b) { g0[b] = 0.f; g1[b] = 0.f; }
    float s0 = 0.f, s1 = 0.f;
    int cur = -1, cnt = 0;
    for (int base = s; base < e; base += 64) {
        int m = e - base;
        if (m > 64) m = 64;
        int pk = 0;
        if (base + lane < e) pk = pcols[base + lane];
        for (int i = 0; i < m; ++i) {
            int v = __builtin_amdgcn_readlane(pk, i);   // SGPR
            int rel = (int)((unsigned)v >> 26);
            if (rel != cur) {                           // wave-uniform branch
                if (cur >= 0) {
                    float w = __builtin_amdgcn_rcpf((float)cnt);
                    float t0 = s0 * w, t1 = s1 * w;
                    const float* cr = csh + cur * kBas;
#pragma unroll
                    for (int b = 0; b < kBas; ++b) {
                        float c = cr[b];                // broadcast ds_read
                        g0[b] += c * t0;
                        g1[b] += c * t1;
                    }
                }
                cur = rel;
                s0 = 0.f; s1 = 0.f; cnt = 0;
            }
            int col = v & 0x03FFFFFF;                   // scalar
            unsigned u = *(const unsigned*)(xsrc + (size_t)col * 128 + 2 * lane);
            s0 += __uint_as_float(u << 16);
            s1 += __uint_as_float(u & 0xffff0000u);
            ++cnt;
        }
    }
    if (cur >= 0) {
        float w = __builtin_amdgcn_rcpf((float)cnt);
        float t0 = s0 * w, t1 = s1 * w;
        const float* cr = csh + cur * kBas;
#pragma unroll
        for (int b = 0; b < kBas; ++b) {
            float c = cr[b];
            g0[b] += c * t0;
            g1[b] += c * t1;
        }
    }
    unsigned short* grow = Gall + (size_t)n * (kBas * 128) + 2 * lane;
#pragma unroll
    for (int b = 0; b < kBas; ++b) {
        unsigned outp = (unsigned)f2bf_rg(g0[b]) | ((unsigned)f2bf_rg(g1[b]) << 16);
        *(unsigned*)(grow + b * 128) = outp;
    }
}

// fused GEMM: out[n][o] = [Gall[n] (K=1024) | x[n] (K=128)] @ wallT[seg][o][k]
// + bias, then LayerNorm + ReLU in-epilogue. 64-row C-tile, 4 waves each
// owning a 64x32 column slice (16x16x32 bf16 MFMA; C map m89/m91:
// col=lane&15, row=(lane>>4)*4+reg). Double-buffered global_load_lds A-tile
// with row-XOR swizzle (both-sides); per segment: B-loads FIRST, then
// stage(seg+1), then quadrant-wise ds_read+MFMA, then vmcnt(0)+barrier.
__global__ __launch_bounds__(256, 3) void fusegemm_rg(const unsigned short* Gall,
                                                      const unsigned short* x,
                                                      const unsigned short* wallT,
                                                      const void* bias, const void* gw,
                                                      const void* bw, const int* dflag,
                                                      unsigned short* out_b, float* out_f,
                                                      int ofp32, int M) {
    __shared__ __align__(16) unsigned short As[2][64][128];   // linear, swizzled
    __shared__ float pS[64][5];
    __shared__ float pQ[64][5];
    __shared__ float mrs[64][2];
    const int m0 = blockIdx.x * 64;
    const int tid = threadIdx.x;
    const int wave = tid >> 6;
    const int lane = tid & 63;
    const int wn = wave * 32;
    const int lrow = lane & 15;
    const int lq = lane >> 4;

    // stage segment seg into As[buf]: 4 x global_load_lds(16B) per thread.
    // LDS granule gi=(wave*4+it)*64+lane -> row=gi>>4, slot=gi&15 (linear dest);
    // source within-row byte = slot*16 ^ ((row&7)<<4)  (pre-swizzle, rule #21).
    auto stage = [&](int seg, int buf) {
        const char* srcb;
        size_t rstrideB, segoffB;
        if (seg < kBas) { srcb = (const char*)Gall; rstrideB = kBas * 256; segoffB = (size_t)seg * 256; }
        else            { srcb = (const char*)x;    rstrideB = 256;        segoffB = 0; }
#pragma unroll
        for (int it = 0; it < 4; ++it) {
            int gi = (wave * 4 + it) * 64 + lane;
            int row = gi >> 4;
            int c = ((gi & 15) << 4) ^ ((row & 7) << 4);
            int gr = m0 + row;
            if (gr > M - 1) gr = M - 1;
            const char* src = srcb + (size_t)gr * rstrideB + segoffB + (size_t)c;
            unsigned short* ldst = &As[buf][0][0] + ((wave * 4 + it) << 9);
            gload_lds16(src, ldst);
        }
    };

    f32x4 acc[4][2] = {};
    // prologue: stage segment 0, drain, barrier
    stage(0, 0);
    asm volatile("s_waitcnt vmcnt(0)" ::: "memory");
    __builtin_amdgcn_s_barrier();
    int cur = 0;
    for (int seg = 0; seg < kSeg; ++seg) {
        // B-loads FIRST (oldest in vmcnt queue -> their wait doesn't drain stage)
        const unsigned short* Bsrc = wallT + (size_t)seg * 16384;
        bf16x8 b[4][2];
#pragma unroll
        for (int kk4 = 0; kk4 < 4; ++kk4)
#pragma unroll
            for (int nt = 0; nt < 2; ++nt)
                b[kk4][nt] = *(const bf16x8*)(Bsrc + (size_t)(wn + nt * 16 + lrow) * 128
                                              + kk4 * 32 + lq * 8);
        __builtin_amdgcn_sched_barrier(0);   // pin: b-loads issue before stage
        if (seg < kSeg - 1) stage(seg + 1, cur ^ 1);
#pragma unroll
        for (int kk4 = 0; kk4 < 4; ++kk4) {
            bf16x8 a4[4];
#pragma unroll
            for (int mt = 0; mt < 4; ++mt) {
                int row = mt * 16 + lrow;
                int cb = (kk4 * 64 + lq * 16) ^ ((row & 7) << 4);
                a4[mt] = *(const bf16x8*)((const char*)&As[cur][0][0]
                                          + row * 256 + cb);
            }
#pragma unroll
            for (int mt = 0; mt < 4; ++mt)
#pragma unroll
                for (int nt = 0; nt < 2; ++nt)
                    acc[mt][nt] = __builtin_amdgcn_mfma_f32_16x16x32_bf16(
                        a4[mt], b[kk4][nt], acc[mt][nt], 0, 0, 0);
        }
        asm volatile("s_waitcnt vmcnt(0)" ::: "memory");
        __builtin_amdgcn_s_barrier();
        cur ^= 1;
    }

    // epilogue: +bias, row mean/var across 128 cols (4 waves x 32 cols), LN+ReLU
    const int f = *dflag;
    float bv[2], gv[2], betav[2];
#pragma unroll
    for (int nt = 0; nt < 2; ++nt) {
        int gc = wn + nt * 16 + lrow;
        if (f) {
            bv[nt] = ((const float*)bias)[gc];
            gv[nt] = ((const float*)gw)[gc];
            betav[nt] = ((const float*)bw)[gc];
        } else {
            bv[nt] = bf2f_rg(((const unsigned short*)bias)[gc]);
            gv[nt] = bf2f_rg(((const unsigned short*)gw)[gc]);
            betav[nt] = bf2f_rg(((const unsigned short*)bw)[gc]);
        }
    }
#pragma unroll
    for (int mt = 0; mt < 4; ++mt)
#pragma unroll
        for (int i = 0; i < 4; ++i) {
            float sv = 0.f, qv = 0.f;
#pragma unroll
            for (int nt = 0; nt < 2; ++nt) {
                float v = acc[mt][nt][i] + bv[nt];
                acc[mt][nt][i] = v;
                sv += v;
                qv += v * v;
            }
            for (int o = 1; o < 16; o <<= 1) {
                sv += __shfl_xor(sv, o);
                qv += __shfl_xor(qv, o);
            }
            if (lrow == 0) {
                int row = mt * 16 + lq * 4 + i;
                pS[row][wave] = sv;
                pQ[row][wave] = qv;
            }
        }
    __syncthreads();
    if (tid < 64) {
        float s4 = pS[tid][0] + pS[tid][1] + pS[tid][2] + pS[tid][3];
        float q4 = pQ[tid][0] + pQ[tid][1] + pQ[tid][2] + pQ[tid][3];
        float mean = s4 * (1.0f / 128.0f);
        float var = q4 * (1.0f / 128.0f) - mean * mean;
        mrs[tid][0] = mean;
        mrs[tid][1] = rsqrtf(var + 1e-5f);
    }
    __syncthreads();
#pragma unroll
    for (int mt = 0; mt < 4; ++mt)
#pragma unroll
        for (int i = 0; i < 4; ++i) {
            int row = mt * 16 + lq * 4 + i;
            int gr = m0 + row;
            if (gr < M) {
                float mean = mrs[row][0];
                float rs = mrs[row][1];
#pragma unroll
                for (int nt = 0; nt < 2; ++nt) {
                    int gc = wn + nt * 16 + lrow;
                    float o = fmaxf((acc[mt][nt][i] - mean) * rs * gv[nt] + betav[nt], 0.f);
                    if (ofp32)
                        out_f[(size_t)gr * 128 + gc] = o;
                    else
                        out_b[(size_t)gr * 128 + gc] = f2bf_rg(o);
                }
            }
        }
}

extern "C" void kernel_launch(void* const* d_in, const int* in_sizes, int n_in,
                              void* d_out, int out_size, void* d_ws, size_t ws_size,
                              hipStream_t stream) {
    const int* ei = (const int*)d_in[0];            // [2,E] int32
    const int* et = (const int*)d_in[1];            // [E] int32
    const void* emb    = d_in[2];
    const void* bases1 = d_in[3];
    const void* coef1  = d_in[4];
    const void* selfw1 = d_in[5];
    const void* bias1  = d_in[6];
    const void* g1     = d_in[7];
    const void* b1     = d_in[8];
    const void* bases2 = d_in[9];
    const void* coef2  = d_in[10];
    const void* selfw2 = d_in[11];
    const void* bias2  = d_in[12];
    const void* g2     = d_in[13];
    const void* b2     = d_in[14];

    const int E = in_sizes[1];
    const int N = out_size / kDim;
    const int n16 = N * kRel;
    const int nsb = (n16 + 255) / 256;

    // workspace (256B-aligned). Gall = [N][1024] bf16 (102.4MB).
    char* ws = (char*)d_ws;
    size_t off = 0;
    int* dflag   = (int*)(ws + off); off += 256;
    float* coefw = (float*)(ws + off); off += 512;
    int* rowptr2 = (int*)(ws + off); off += (((size_t)n16 + 1) * 4 + 255) & ~(size_t)255;
    int* cnt     = (int*)(ws + off); off += ((size_t)n16 * 4 + 255) & ~(size_t)255;
    int* bsum    = (int*)(ws + off); off += ((size_t)nsb * 4 + 255) & ~(size_t)255;
    int* pcols   = (int*)(ws + off); off += ((size_t)E * 4 + 255) & ~(size_t)255;
    unsigned short* wallT = (unsigned short*)(ws + off);
    off += ((size_t)kSeg * 16384 * 2 + 255) & ~(size_t)255;
    unsigned short* xin  = (unsigned short*)(ws + off);
    off += ((size_t)N * 128 * 2 + 255) & ~(size_t)255;
    unsigned short* xmid = (unsigned short*)(ws + off);
    off += ((size_t)N * 128 * 2 + 255) & ~(size_t)255;
    unsigned short* Gall = (unsigned short*)(ws + off);
    (void)n_in; (void)ws_size;

    const int eblk = (E + 255) / 256;
    const int mblk64 = (N + 63) / 64;
    const int ablk = (N + 3) / 4;
    const int nelem = N * 128;

    // sentinel (template symbol; fully overwritten by fusegemm layer 2)
    RGCNEncoder_89962384982025_kernel<<<(out_size / 2 + 255) / 256, 256, 0, stream>>>(
        (unsigned*)d_out, out_size / 2);

    // dtype detection + emb -> bf16
    detect_rg<<<1, 64, 0, stream>>>((const unsigned short*)emb, dflag);
    cvt_rg<<<(nelem + 255) / 256, 256, 0, stream>>>(emb, dflag, xin, nelem);

    // CSR by (node, relation); in-place hierarchical scan
    zero_rg<<<(n16 + 255) / 256, 256, 0, stream>>>(cnt, n16);
    count_rg<<<eblk, 256, 0, stream>>>(ei, et, cnt, E);
    scanA_rg<<<nsb, 256, 0, stream>>>(cnt, rowptr2, bsum, n16);
    scanB_rg<<<1, 256, 0, stream>>>(bsum, nsb);
    scanC_rg<<<nsb, 256, 0, stream>>>(rowptr2, bsum, n16);
    fill_rg<<<eblk, 256, 0, stream>>>(ei, et, rowptr2, cnt, pcols, E);

    // layer 1: aggregate xin -> Gall (basis space), fused GEMM -> bf16 xmid
    wall_rg<<<kSeg * 64, 256, 0, stream>>>(bases1, coef1, selfw1, dflag, wallT, coefw);
    agg2_rg<<<ablk, 256, 0, stream>>>(rowptr2, pcols, xin, coefw, Gall, N);
    fusegemm_rg<<<mblk64, 256, 0, stream>>>(Gall, xin, wallT, bias1, g1, b1, dflag,
                                            xmid, (float*)nullptr, 0, N);

    // layer 2: aggregate xmid -> Gall, fused GEMM -> fp32 d_out
    wall_rg<<<kSeg * 64, 256, 0, stream>>>(bases2, coef2, selfw2, dflag, wallT, coefw);
    agg2_rg<<<ablk, 256, 0, stream>>>(rowptr2, pcols, xmid, coefw, Gall, N);
    fusegemm_rg<<<mblk64, 256, 0, stream>>>(Gall, xmid, wallT, bias2, g2, b2, dflag,
                                            (unsigned short*)nullptr, (float*)d_out,
                                            1, N);
}

// Round 6
// 374.378 us; speedup vs baseline: 1.5065x; 1.1041x over previous
//
#include <hip/hip_runtime.h>
#include <hip/hip_bf16.h>

// RGCN 2-layer encoder. N=50000, R=16, B=8, Dim=128, E=625000.
// fp32 in/out (runtime-detected), bf16 MFMA internals.
//
// R21: agg2 was latency-bound on the serial edge gather (R20: 51% VALU,
// 36% HBM, ~1 load in flight). Now depth-4 batched: 4 readlanes + 4
// independent gather loads issued back-to-back, THEN bucket logic on the
// returned values -> 4x memory-level parallelism in the serial stream.
// detect_rg kernel deleted (consumers derive dtype flag inline from emb's
// first 128 halves: one wave, 2 loads + ballot); sentinel fill shrunk to
// one block (d_out fully overwritten by layer-2 fusegemm). 15 dispatches.
//
// Pipeline per layer: wallT[b][o][k]=bases[b]^T (slot8=selfw^T) + coefw fp32;
// agg2: wave-per-node CSR scan -> Gall[n][b*128+o] (basis space, 102MB);
// fusegemm: out[n][o] = [Gall[n] | x[n]] @ wallT (K=1152), epilogue LN+ReLU.

static constexpr int kDim = 128;
static constexpr int kRel = 16;
static constexpr int kBas = 8;
static constexpr int kSeg = kBas + 1;   // 8 bases + self

typedef __attribute__((ext_vector_type(8))) short bf16x8;
typedef __attribute__((ext_vector_type(4))) float f32x4;

static __device__ __forceinline__ float bf2f_rg(unsigned short h) {
    return __uint_as_float(((unsigned)h) << 16);
}
static __device__ __forceinline__ unsigned short f2bf_rg(float f) {
    unsigned u = __float_as_uint(f);
    u = u + 0x7fffu + ((u >> 16) & 1u);   // round-to-nearest-even
    return (unsigned short)(u >> 16);
}

static __device__ __forceinline__ void gload_lds16(const void* g, void* l) {
    __builtin_amdgcn_global_load_lds(
        (const __attribute__((address_space(1))) unsigned*)g,
        (__attribute__((address_space(3))) unsigned*)l, 16, 0, 0);
}

// dtype flag from emb's first 128 halves (call with one full wave, tid<64):
// any bf16-decoded exponent >= 0x86 (|v|>=128/inf/nan) => input is fp32
static __device__ __forceinline__ int flag_from(const unsigned short* x, int lane) {
    unsigned e0 = ((unsigned)x[lane] >> 7) & 0xFFu;
    unsigned e1 = ((unsigned)x[lane + 64] >> 7) & 0xFFu;
    int bad = (e0 >= 0x86u) || (e1 >= 0x86u);
    return (__ballot(bad) != 0ull) ? 1 : 0;
}

// template-named kernel: sentinel stub (d_out fully overwritten by pipeline)
__global__ void RGCNEncoder_89962384982025_kernel(unsigned* p, int n) {
    int i = blockIdx.x * 256 + threadIdx.x;
    if (i < n) p[i] = 0x3F803F80u;
}

// convert emb (fp32 or bf16, flag derived inline) -> bf16 xin
__global__ void cvt_rg(const void* xraw, unsigned short* xout, int n) {
    __shared__ int fsh;
    if (threadIdx.x < 64) {
        int fl = flag_from((const unsigned short*)xraw, threadIdx.x);
        if (threadIdx.x == 0) fsh = fl;
    }
    __syncthreads();
    int f = fsh;
    int i = blockIdx.x * 256 + threadIdx.x;
    if (i >= n) return;
    if (f)
        xout[i] = f2bf_rg(((const float*)xraw)[i]);
    else
        xout[i] = ((const unsigned short*)xraw)[i];
}

__global__ void zero_rg(int* p, int n) {
    int i = blockIdx.x * 256 + threadIdx.x;
    if (i < n) p[i] = 0;
}

__global__ void count_rg(const int* ei, const int* et, int* cnt, int E) {
    int e = blockIdx.x * 256 + threadIdx.x;
    if (e < E) atomicAdd(&cnt[ei[e] * kRel + et[e]], 1);
}

// hierarchical scan, in place on rowptr (saves the incl buffer)
__global__ void scanA_rg(const int* cnt, int* rowptr, int* bsum, int n) {
    __shared__ int sh[256];
    int tid = threadIdx.x;
    int i = blockIdx.x * 256 + tid;
    int v = (i < n) ? cnt[i] : 0;
    sh[tid] = v;
    __syncthreads();
    for (int off = 1; off < 256; off <<= 1) {
        int t = (tid >= off) ? sh[tid - off] : 0;
        __syncthreads();
        sh[tid] += t;
        __syncthreads();
    }
    if (i < n) rowptr[i + 1] = sh[tid];
    if (tid == 255) bsum[blockIdx.x] = sh[255];
}
__global__ void scanB_rg(int* bsum, int nb) {
    __shared__ int partial[256];
    int tid = threadIdx.x;
    int chunk = (nb + 255) / 256;
    int s0 = tid * chunk;
    int s1 = min(s0 + chunk, nb);
    int sum = 0;
    for (int i = s0; i < s1; ++i) sum += bsum[i];
    partial[tid] = sum;
    __syncthreads();
    for (int off = 1; off < 256; off <<= 1) {
        int t = (tid >= off) ? partial[tid - off] : 0;
        __syncthreads();
        partial[tid] += t;
        __syncthreads();
    }
    int run = (tid == 0) ? 0 : partial[tid - 1];
    for (int i = s0; i < s1; ++i) { int v = bsum[i]; bsum[i] = run; run += v; }
}
__global__ void scanC_rg(int* rowptr, const int* bsum, int n) {
    int i = blockIdx.x * 256 + threadIdx.x;
    if (i < n) rowptr[i + 1] += bsum[blockIdx.x];
    if (i == 0) rowptr[0] = 0;
}

// fill: pcols entry packs col | rel<<26 (col < 2^26)
__global__ void fill_rg(const int* ei, const int* et, const int* rowptr,
                        int* cnt, int* pcols, int E) {
    int e = blockIdx.x * 256 + threadIdx.x;
    if (e < E) {
        int rel = et[e];
        int key = ei[e] * kRel + rel;
        int old = atomicSub(&cnt[key], 1);
        pcols[rowptr[key] + old - 1] = ei[E + e] | (rel << 26);
    }
}

// wallT[b][o][k] = bases[b][k][o] for b<8; slot 8 = selfw^T.
// Also stages coef decoded to fp32 (coefw[16][8]) for agg2's LDS mix table.
__global__ void wall_rg(const void* bases, const void* coef, const void* selfw,
                        const unsigned short* emb, unsigned short* wallT,
                        float* coefw) {
    __shared__ int fsh;
    if (threadIdx.x < 64) {
        int fl = flag_from(emb, threadIdx.x);
        if (threadIdx.x == 0) fsh = fl;
    }
    __syncthreads();
    int f = fsh;
    int idx = blockIdx.x * 256 + threadIdx.x;   // b*16384 + o*128 + k
    int b = idx >> 14;
    int o = (idx >> 7) & 127;
    int k = idx & 127;
    if (blockIdx.x == 0 && threadIdx.x < kRel * kBas) {
        coefw[threadIdx.x] = f ? ((const float*)coef)[threadIdx.x]
                               : bf2f_rg(((const unsigned short*)coef)[threadIdx.x]);
    }
    if (b < kBas) {
        float bv = f ? ((const float*)bases)[b * 16384 + k * 128 + o]
                     : bf2f_rg(((const unsigned short*)bases)[b * 16384 + k * 128 + o]);
        wallT[idx] = f2bf_rg(bv);
    } else {
        float sv = f ? ((const float*)selfw)[k * 128 + o]
                     : bf2f_rg(((const unsigned short*)selfw)[k * 128 + o]);
        wallT[idx] = f2bf_rg(sv);
    }
}

// aggregate-first in basis space: Gall[n][b*128+o] = sum_r coefw[r][b] *
// mean over r-bucket edges of x[col][o]. Wave per node (4 waves/block).
// Depth-4 batched gather: 4 readlanes + 4 independent loads in flight,
// then bucket-transition logic on the returned values (latency overlap).
__global__ __launch_bounds__(256) void agg2_rg(const int* rowptr2, const int* pcols,
                                               const unsigned short* xsrc,
                                               const float* coefw,
                                               unsigned short* Gall, int N) {
    __shared__ float csh[kRel * kBas];
    if (threadIdx.x < kRel * kBas) csh[threadIdx.x] = coefw[threadIdx.x];
    __syncthreads();
    int wv = threadIdx.x >> 6;
    int lane = threadIdx.x & 63;
    int n = blockIdx.x * 4 + wv;
    if (n >= N) return;
    const int s = rowptr2[n * kRel];          // wave-uniform -> scalar load
    const int e = rowptr2[n * kRel + kRel];
    const unsigned short* xl = xsrc + 2 * lane;
    float g0[kBas], g1[kBas];
#pragma unroll
    for (int b = 0; b < kBas; ++b) { g0[b] = 0.f; g1[b] = 0.f; }
    float s0 = 0.f, s1 = 0.f;
    int cur = -1, cnt = 0;
    auto flush = [&]() {
        float w = __builtin_amdgcn_rcpf((float)cnt);
        float t0 = s0 * w, t1 = s1 * w;
        const float* cr = csh + cur * kBas;
#pragma unroll
        for (int b = 0; b < kBas; ++b) {
            float c = cr[b];                  // broadcast ds_read
            g0[b] += c * t0;
            g1[b] += c * t1;
        }
        s0 = 0.f; s1 = 0.f; cnt = 0;
    };
    for (int base = s; base < e; base += 64) {
        int m = e - base;
        if (m > 64) m = 64;
        int pk = 0;
        if (base + lane < e) pk = pcols[base + lane];
        int i = 0;
        for (; i + 4 <= m; i += 4) {
            // issue 4 independent gathers back-to-back (4 in flight)
            int v0 = __builtin_amdgcn_readlane(pk, i);
            int v1 = __builtin_amdgcn_readlane(pk, i + 1);
            int v2 = __builtin_amdgcn_readlane(pk, i + 2);
            int v3 = __builtin_amdgcn_readlane(pk, i + 3);
            unsigned u0 = *(const unsigned*)(xl + (size_t)(v0 & 0x03FFFFFF) * 128);
            unsigned u1 = *(const unsigned*)(xl + (size_t)(v1 & 0x03FFFFFF) * 128);
            unsigned u2 = *(const unsigned*)(xl + (size_t)(v2 & 0x03FFFFFF) * 128);
            unsigned u3 = *(const unsigned*)(xl + (size_t)(v3 & 0x03FFFFFF) * 128);
            int r0 = (int)((unsigned)v0 >> 26);
            int r1 = (int)((unsigned)v1 >> 26);
            int r2 = (int)((unsigned)v2 >> 26);
            int r3 = (int)((unsigned)v3 >> 26);
            if (r0 != cur) { if (cnt) flush(); cur = r0; }
            s0 += __uint_as_float(u0 << 16); s1 += __uint_as_float(u0 & 0xffff0000u); ++cnt;
            if (r1 != cur) { flush(); cur = r1; }
            s0 += __uint_as_float(u1 << 16); s1 += __uint_as_float(u1 & 0xffff0000u); ++cnt;
            if (r2 != cur) { flush(); cur = r2; }
            s0 += __uint_as_float(u2 << 16); s1 += __uint_as_float(u2 & 0xffff0000u); ++cnt;
            if (r3 != cur) { flush(); cur = r3; }
            s0 += __uint_as_float(u3 << 16); s1 += __uint_as_float(u3 & 0xffff0000u); ++cnt;
        }
        for (; i < m; ++i) {
            int v = __builtin_amdgcn_readlane(pk, i);
            unsigned u = *(const unsigned*)(xl + (size_t)(v & 0x03FFFFFF) * 128);
            int rel = (int)((unsigned)v >> 26);
            if (rel != cur) { if (cnt) flush(); cur = rel; }
            s0 += __uint_as_float(u << 16);
            s1 += __uint_as_float(u & 0xffff0000u);
            ++cnt;
        }
    }
    if (cnt) flush();
    unsigned short* grow = Gall + (size_t)n * (kBas * 128) + 2 * lane;
#pragma unroll
    for (int b = 0; b < kBas; ++b) {
        unsigned outp = (unsigned)f2bf_rg(g0[b]) | ((unsigned)f2bf_rg(g1[b]) << 16);
        *(unsigned*)(grow + b * 128) = outp;
    }
}

// fused GEMM: out[n][o] = [Gall[n] (K=1024) | x[n] (K=128)] @ wallT[seg][o][k]
// + bias, then LayerNorm + ReLU in-epilogue. 64-row C-tile, 4 waves each
// owning a 64x32 column slice (16x16x32 bf16 MFMA; C map m89/m91:
// col=lane&15, row=(lane>>4)*4+reg). Double-buffered global_load_lds A-tile
// with row-XOR swizzle (both-sides); per segment: B-loads FIRST, then
// stage(seg+1), then quadrant-wise ds_read+MFMA, then vmcnt(0)+barrier.
__global__ __launch_bounds__(256, 3) void fusegemm_rg(const unsigned short* Gall,
                                                      const unsigned short* x,
                                                      const unsigned short* wallT,
                                                      const void* bias, const void* gw,
                                                      const void* bw,
                                                      const unsigned short* emb,
                                                      unsigned short* out_b, float* out_f,
                                                      int ofp32, int M) {
    __shared__ __align__(16) unsigned short As[2][64][128];   // linear, swizzled
    __shared__ float pS[64][5];
    __shared__ float pQ[64][5];
    __shared__ float mrs[64][2];
    __shared__ int fsh;
    const int m0 = blockIdx.x * 64;
    const int tid = threadIdx.x;
    const int wave = tid >> 6;
    const int lane = tid & 63;
    const int wn = wave * 32;
    const int lrow = lane & 15;
    const int lq = lane >> 4;
    if (tid < 64) {
        int fl = flag_from(emb, tid);
        if (tid == 0) fsh = fl;
    }

    // stage segment seg into As[buf]: 4 x global_load_lds(16B) per thread.
    // LDS granule gi=(wave*4+it)*64+lane -> row=gi>>4, slot=gi&15 (linear dest);
    // source within-row byte = slot*16 ^ ((row&7)<<4)  (pre-swizzle, rule #21).
    auto stage = [&](int seg, int buf) {
        const char* srcb;
        size_t rstrideB, segoffB;
        if (seg < kBas) { srcb = (const char*)Gall; rstrideB = kBas * 256; segoffB = (size_t)seg * 256; }
        else            { srcb = (const char*)x;    rstrideB = 256;        segoffB = 0; }
#pragma unroll
        for (int it = 0; it < 4; ++it) {
            int gi = (wave * 4 + it) * 64 + lane;
            int row = gi >> 4;
            int c = ((gi & 15) << 4) ^ ((row & 7) << 4);
            int gr = m0 + row;
            if (gr > M - 1) gr = M - 1;
            const char* src = srcb + (size_t)gr * rstrideB + segoffB + (size_t)c;
            unsigned short* ldst = &As[buf][0][0] + ((wave * 4 + it) << 9);
            gload_lds16(src, ldst);
        }
    };

    f32x4 acc[4][2] = {};
    // prologue: stage segment 0, drain + publish fsh
    stage(0, 0);
    __syncthreads();
    int cur = 0;
    for (int seg = 0; seg < kSeg; ++seg) {
        // B-loads FIRST (oldest in vmcnt queue -> their wait doesn't drain stage)
        const unsigned short* Bsrc = wallT + (size_t)seg * 16384;
        bf16x8 b[4][2];
#pragma unroll
        for (int kk4 = 0; kk4 < 4; ++kk4)
#pragma unroll
            for (int nt = 0; nt < 2; ++nt)
                b[kk4][nt] = *(const bf16x8*)(Bsrc + (size_t)(wn + nt * 16 + lrow) * 128
                                              + kk4 * 32 + lq * 8);
        __builtin_amdgcn_sched_barrier(0);   // pin: b-loads issue before stage
        if (seg < kSeg - 1) stage(seg + 1, cur ^ 1);
#pragma unroll
        for (int kk4 = 0; kk4 < 4; ++kk4) {
            bf16x8 a4[4];
#pragma unroll
            for (int mt = 0; mt < 4; ++mt) {
                int row = mt * 16 + lrow;
                int cb = (kk4 * 64 + lq * 16) ^ ((row & 7) << 4);
                a4[mt] = *(const bf16x8*)((const char*)&As[cur][0][0]
                                          + row * 256 + cb);
            }
#pragma unroll
            for (int mt = 0; mt < 4; ++mt)
#pragma unroll
                for (int nt = 0; nt < 2; ++nt)
                    acc[mt][nt] = __builtin_amdgcn_mfma_f32_16x16x32_bf16(
                        a4[mt], b[kk4][nt], acc[mt][nt], 0, 0, 0);
        }
        asm volatile("s_waitcnt vmcnt(0)" ::: "memory");
        __builtin_amdgcn_s_barrier();
        cur ^= 1;
    }

    // epilogue: +bias, row mean/var across 128 cols (4 waves x 32 cols), LN+ReLU
    const int f = fsh;
    float bv[2], gv[2], betav[2];
#pragma unroll
    for (int nt = 0; nt < 2; ++nt) {
        int gc = wn + nt * 16 + lrow;
        if (f) {
            bv[nt] = ((const float*)bias)[gc];
            gv[nt] = ((const float*)gw)[gc];
            betav[nt] = ((const float*)bw)[gc];
        } else {
            bv[nt] = bf2f_rg(((const unsigned short*)bias)[gc]);
            gv[nt] = bf2f_rg(((const unsigned short*)gw)[gc]);
            betav[nt] = bf2f_rg(((const unsigned short*)bw)[gc]);
        }
    }
#pragma unroll
    for (int mt = 0; mt < 4; ++mt)
#pragma unroll
        for (int i = 0; i < 4; ++i) {
            float sv = 0.f, qv = 0.f;
#pragma unroll
            for (int nt = 0; nt < 2; ++nt) {
                float v = acc[mt][nt][i] + bv[nt];
                acc[mt][nt][i] = v;
                sv += v;
                qv += v * v;
            }
            for (int o = 1; o < 16; o <<= 1) {
                sv += __shfl_xor(sv, o);
                qv += __shfl_xor(qv, o);
            }
            if (lrow == 0) {
                int row = mt * 16 + lq * 4 + i;
                pS[row][wave] = sv;
                pQ[row][wave] = qv;
            }
        }
    __syncthreads();
    if (tid < 64) {
        float s4 = pS[tid][0] + pS[tid][1] + pS[tid][2] + pS[tid][3];
        float q4 = pQ[tid][0] + pQ[tid][1] + pQ[tid][2] + pQ[tid][3];
        float mean = s4 * (1.0f / 128.0f);
        float var = q4 * (1.0f / 128.0f) - mean * mean;
        mrs[tid][0] = mean;
        mrs[tid][1] = rsqrtf(var + 1e-5f);
    }
    __syncthreads();
#pragma unroll
    for (int mt = 0; mt < 4; ++mt)
#pragma unroll
        for (int i = 0; i < 4; ++i) {
            int row = mt * 16 + lq * 4 + i;
            int gr = m0 + row;
            if (gr < M) {
                float mean = mrs[row][0];
                float rs = mrs[row][1];
#pragma unroll
                for (int nt = 0; nt < 2; ++nt) {
                    int gc = wn + nt * 16 + lrow;
                    float o = fmaxf((acc[mt][nt][i] - mean) * rs * gv[nt] + betav[nt], 0.f);
                    if (ofp32)
                        out_f[(size_t)gr * 128 + gc] = o;
                    else
                        out_b[(size_t)gr * 128 + gc] = f2bf_rg(o);
                }
            }
        }
}

extern "C" void kernel_launch(void* const* d_in, const int* in_sizes, int n_in,
                              void* d_out, int out_size, void* d_ws, size_t ws_size,
                              hipStream_t stream) {
    const int* ei = (const int*)d_in[0];            // [2,E] int32
    const int* et = (const int*)d_in[1];            // [E] int32
    const void* emb    = d_in[2];
    const void* bases1 = d_in[3];
    const void* coef1  = d_in[4];
    const void* selfw1 = d_in[5];
    const void* bias1  = d_in[6];
    const void* g1     = d_in[7];
    const void* b1     = d_in[8];
    const void* bases2 = d_in[9];
    const void* coef2  = d_in[10];
    const void* selfw2 = d_in[11];
    const void* bias2  = d_in[12];
    const void* g2     = d_in[13];
    const void* b2     = d_in[14];

    const int E = in_sizes[1];
    const int N = out_size / kDim;
    const int n16 = N * kRel;
    const int nsb = (n16 + 255) / 256;

    // workspace (256B-aligned). Gall = [N][1024] bf16 (102.4MB).
    char* ws = (char*)d_ws;
    size_t off = 0;
    float* coefw = (float*)(ws + off); off += 512;
    int* rowptr2 = (int*)(ws + off); off += (((size_t)n16 + 1) * 4 + 255) & ~(size_t)255;
    int* cnt     = (int*)(ws + off); off += ((size_t)n16 * 4 + 255) & ~(size_t)255;
    int* bsum    = (int*)(ws + off); off += ((size_t)nsb * 4 + 255) & ~(size_t)255;
    int* pcols   = (int*)(ws + off); off += ((size_t)E * 4 + 255) & ~(size_t)255;
    unsigned short* wallT = (unsigned short*)(ws + off);
    off += ((size_t)kSeg * 16384 * 2 + 255) & ~(size_t)255;
    unsigned short* xin  = (unsigned short*)(ws + off);
    off += ((size_t)N * 128 * 2 + 255) & ~(size_t)255;
    unsigned short* xmid = (unsigned short*)(ws + off);
    off += ((size_t)N * 128 * 2 + 255) & ~(size_t)255;
    unsigned short* Gall = (unsigned short*)(ws + off);
    (void)n_in; (void)ws_size;

    const int eblk = (E + 255) / 256;
    const int mblk64 = (N + 63) / 64;
    const int ablk = (N + 3) / 4;
    const int nelem = N * 128;
    const unsigned short* embh = (const unsigned short*)emb;

    // sentinel stub (template symbol; d_out fully overwritten by layer 2)
    RGCNEncoder_89962384982025_kernel<<<1, 256, 0, stream>>>((unsigned*)d_out, 256);

    // emb -> bf16 (dtype flag derived inline)
    cvt_rg<<<(nelem + 255) / 256, 256, 0, stream>>>(emb, xin, nelem);

    // CSR by (node, relation); in-place hierarchical scan
    zero_rg<<<(n16 + 255) / 256, 256, 0, stream>>>(cnt, n16);
    count_rg<<<eblk, 256, 0, stream>>>(ei, et, cnt, E);
    scanA_rg<<<nsb, 256, 0, stream>>>(cnt, rowptr2, bsum, n16);
    scanB_rg<<<1, 256, 0, stream>>>(bsum, nsb);
    scanC_rg<<<nsb, 256, 0, stream>>>(rowptr2, bsum, n16);
    fill_rg<<<eblk, 256, 0, stream>>>(ei, et, rowptr2, cnt, pcols, E);

    // layer 1: aggregate xin -> Gall (basis space), fused GEMM -> bf16 xmid
    wall_rg<<<kSeg * 64, 256, 0, stream>>>(bases1, coef1, selfw1, embh, wallT, coefw);
    agg2_rg<<<ablk, 256, 0, stream>>>(rowptr2, pcols, xin, coefw, Gall, N);
    fusegemm_rg<<<mblk64, 256, 0, stream>>>(Gall, xin, wallT, bias1, g1, b1, embh,
                                            xmid, (float*)nullptr, 0, N);

    // layer 2: aggregate xmid -> Gall, fused GEMM -> fp32 d_out
    wall_rg<<<kSeg * 64, 256, 0, stream>>>(bases2, coef2, selfw2, embh, wallT, coefw);
    agg2_rg<<<ablk, 256, 0, stream>>>(rowptr2, pcols, xmid, coefw, Gall, N);
    fusegemm_rg<<<mblk64, 256, 0, stream>>>(Gall, xmid, wallT, bias2, g2, b2, embh,
                                            (unsigned short*)nullptr, (float*)d_out,
                                            1, N);
}